// Round 1
// baseline (3171.220 us; speedup 1.0000x reference)
//
#include <hip/hip_runtime.h>
#include <hip/hip_bf16.h>

// CrissCross (axial) attention, B=8 C=256 H=W=96 CQ=32.
// Pipeline:
//  pack_qk   : concat wq|wk -> Wqk[64][256] per input
//  proj_gemm<0>: q,k fp32 planes P[b][64][9216]
//  proj_gemm<1>: v -> bf16 permuted copies vH[b][w][g][c], vW[b][h][v'][c]
//  attn_col  : per (b,w): e_h + full softmax stats (m,1/s) + out_h -> tmp1[b][w][c][h]
//  transpose : tmp1 -> tmp2[b][h][c][w]
//  attn_row  : per (b,h): e_w, apply, out = x + gamma*(out_h+out_w)

#define Bn 8
#define Cn 256
#define Hn 96
#define Wn 96
#define CQ 32
#define NHW 9216
#define QKC 64
#define QK_BS (QKC * NHW)
#define TB 384

typedef unsigned short u16;

__device__ __forceinline__ float bf2f(u16 v) {
  union { unsigned int u; float f; } x; x.u = ((unsigned int)v) << 16; return x.f;
}
__device__ __forceinline__ u16 f2bf(float f) {
  union { unsigned int u; float f; } x; x.f = f;
  unsigned int r = x.u + 0x7fff + ((x.u >> 16) & 1);
  return (u16)(r >> 16);
}

__global__ __launch_bounds__(256) void pack_qk(const float* __restrict__ wq, const float* __restrict__ bq,
                                               const float* __restrict__ wk, const float* __restrict__ bk,
                                               float* __restrict__ Wqk, float* __restrict__ bqk) {
  int i = blockIdx.x * 256 + threadIdx.x;
  if (i < 64 * 256) {
    int o = i >> 8, c = i & 255;
    Wqk[i] = (o < 32) ? wq[o * 256 + c] : wk[(o - 32) * 256 + c];
  }
  if (i < 64) bqk[i] = (i < 32) ? bq[i] : bk[i - 32];
}

// MODE 0: write fp32 Y[b][o][n].  MODE 1: write bf16 vH[b][w][g][c] + vW[b][h][v'][c].
template <int MODE>
__global__ __launch_bounds__(256) void proj_gemm(const float* __restrict__ X, const float* __restrict__ Wm,
                                                 const float* __restrict__ bias, float* __restrict__ Y,
                                                 u16* __restrict__ vH, u16* __restrict__ vW, int Otot) {
  __shared__ float sW[16][68];
  __shared__ float sX[16][68];
  __shared__ u16 sO[64][72];
  int b = blockIdx.z;
  int o0 = blockIdx.y * 64;
  int n0 = blockIdx.x * 64;
  int tid = threadIdx.x;
  int tr = tid >> 4, tc = tid & 15;
  const float* Xb = X + (size_t)b * Cn * NHW;
  float acc[4][4] = {};
  for (int c0 = 0; c0 < Cn; c0 += 16) {
    for (int i = tid; i < 1024; i += 256) {
      int kk = i & 15, oo = i >> 4;
      sW[kk][oo] = Wm[(size_t)(o0 + oo) * Cn + c0 + kk];
    }
    for (int i = tid; i < 1024; i += 256) {
      int nn = i & 63, kk = i >> 6;
      sX[kk][nn] = Xb[(size_t)(c0 + kk) * NHW + n0 + nn];
    }
    __syncthreads();
#pragma unroll
    for (int kk = 0; kk < 16; ++kk) {
      float4 xv = *(const float4*)&sX[kk][tc * 4];
      float4 wv = *(const float4*)&sW[kk][tr * 4];
      float wa[4] = {wv.x, wv.y, wv.z, wv.w};
      float xa[4] = {xv.x, xv.y, xv.z, xv.w};
#pragma unroll
      for (int i = 0; i < 4; ++i)
#pragma unroll
        for (int j = 0; j < 4; ++j) acc[i][j] += wa[i] * xa[j];
    }
    __syncthreads();
  }
  if (MODE == 0) {
    float* Yb = Y + (size_t)b * Otot * NHW;
#pragma unroll
    for (int i = 0; i < 4; ++i) {
      int o = o0 + tr * 4 + i;
      float bv = bias[o];
      float4 r = make_float4(acc[i][0] + bv, acc[i][1] + bv, acc[i][2] + bv, acc[i][3] + bv);
      *(float4*)&Yb[(size_t)o * NHW + n0 + tc * 4] = r;
    }
  } else {
#pragma unroll
    for (int i = 0; i < 4; ++i) {
      float bv = bias[o0 + tr * 4 + i];
#pragma unroll
      for (int j = 0; j < 4; ++j) sO[tc * 4 + j][tr * 4 + i] = f2bf(acc[i][j] + bv);
    }
    __syncthreads();
    for (int idx = tid; idx < 4096; idx += 256) {
      int nn = idx >> 6, cc = idx & 63;
      int n = n0 + nn;
      int ih = n / 96, jw = n % 96;
      u16 val = sO[nn][cc];
      vH[((size_t)(b * 96 + jw) * 96 + ih) * 256 + o0 + cc] = val;
      vW[((size_t)(b * 96 + ih) * 96 + jw) * 256 + o0 + cc] = val;
    }
  }
}

// Column pass: block (b,w). e_h + softmax stats over all 192 logits + out_h.
__global__ __launch_bounds__(TB) void attn_col(const float* __restrict__ Qb, const float* __restrict__ Kb,
                                               const u16* __restrict__ vH, float* __restrict__ mArr,
                                               float* __restrict__ invArr, u16* __restrict__ tmp1) {
  __shared__ float qs[CQ][97], ks[CQ][97];
  __shared__ float ah[96][97];
  __shared__ float sm[96], sinv[96];
  __shared__ u16 vs[96][256];
  int w = blockIdx.x, b = blockIdx.y;
  int tid = threadIdx.x;
  const float* Qp = Qb + (size_t)b * QK_BS;
  const float* Kp = Kb + (size_t)b * QK_BS;
  for (int i = tid; i < CQ * 96; i += TB) {
    int cq = i / 96, hh = i % 96;
    qs[cq][hh] = Qp[cq * NHW + hh * 96 + w];
    ks[cq][hh] = Kp[cq * NHW + hh * 96 + w];
  }
  __syncthreads();
  for (int idx = tid; idx < 9216; idx += TB) {
    int h = idx / 96, g = idx % 96;
    float e = 0.f;
#pragma unroll
    for (int cq = 0; cq < CQ; ++cq) e += qs[cq][h] * ks[cq][g];
    ah[h][g] = (g == h) ? -1e30f : e;
  }
  __syncthreads();
  int wid = tid >> 6, lane = tid & 63;
  for (int h = wid; h < 96; h += TB / 64) {
    float a1 = 0.f, a2 = 0.f;
    const float* kr = Kp + h * 96;
#pragma unroll
    for (int cq = 0; cq < CQ; ++cq) {
      float qv = qs[cq][h];
      a1 += qv * kr[cq * NHW + lane];
      if (lane < 32) a2 += qv * kr[cq * NHW + 64 + lane];
    }
    float e1 = ah[h][lane];
    float e2 = (lane < 32) ? ah[h][64 + lane] : -1e30f;
    float mx = fmaxf(fmaxf(e1, e2), (lane < 32) ? fmaxf(a1, a2) : a1);
#pragma unroll
    for (int off = 32; off; off >>= 1) mx = fmaxf(mx, __shfl_xor(mx, off));
    float s = __expf(e1 - mx) + __expf(a1 - mx);
    if (lane < 32) s += __expf(e2 - mx) + __expf(a2 - mx);
#pragma unroll
    for (int off = 32; off; off >>= 1) s += __shfl_xor(s, off);
    if (lane == 0) {
      float iv = 1.0f / s;
      sm[h] = mx; sinv[h] = iv;
      mArr[((size_t)b * 96 + h) * 96 + w] = mx;
      invArr[((size_t)b * 96 + h) * 96 + w] = iv;
    }
  }
  __syncthreads();
  for (int idx = tid; idx < 9216; idx += TB) {
    int h = idx / 96, g = idx % 96;
    ah[h][g] = __expf(ah[h][g] - sm[h]) * sinv[h];
  }
  const u16* vp = vH + (size_t)(b * 96 + w) * 96 * 256;
  for (int i = tid; i < 96 * 256; i += TB) ((u16*)vs)[i] = vp[i];
  __syncthreads();
  int hh = tid % 96, grp = tid / 96;
  u16* tp = tmp1 + (size_t)(b * 96 + w) * 256 * 96;
  for (int c = grp * 64; c < grp * 64 + 64; ++c) {
    float acc = 0.f;
#pragma unroll 4
    for (int g = 0; g < 96; ++g) acc += bf2f(vs[g][c]) * ah[hh][g];
    tp[(size_t)c * 96 + hh] = f2bf(acc);
  }
}

__global__ __launch_bounds__(256) void transpose_hw(const u16* __restrict__ tmp1, u16* __restrict__ tmp2) {
  __shared__ u16 t[96][98];
  int c = blockIdx.x, b = blockIdx.y;
  int tid = threadIdx.x;
  for (int idx = tid; idx < 9216; idx += 256) {
    int w_ = idx / 96, hh = idx % 96;
    t[w_][hh] = tmp1[((size_t)(b * 96 + w_) * 256 + c) * 96 + hh];
  }
  __syncthreads();
  for (int idx = tid; idx < 9216; idx += 256) {
    int hh = idx / 96, w_ = idx % 96;
    tmp2[((size_t)(b * 96 + hh) * 256 + c) * 96 + w_] = t[w_][hh];
  }
}

// Row pass: block (b,h). Recompute e_w, apply with stored stats, add out_h + residual.
__global__ __launch_bounds__(TB) void attn_row(const float* __restrict__ Qb, const float* __restrict__ Kb,
                                               const u16* __restrict__ vW, const float* __restrict__ mArr,
                                               const float* __restrict__ invArr, const u16* __restrict__ tmp2,
                                               const float* __restrict__ x, const float* __restrict__ gammaP,
                                               float* __restrict__ out) {
  __shared__ float qr[CQ][97], kr[CQ][97];
  __shared__ float aw[96][97];
  __shared__ float smv[96], siv[96];
  __shared__ u16 vs[96][256];
  int h = blockIdx.x, b = blockIdx.y;
  int tid = threadIdx.x;
  const float* Qp = Qb + (size_t)b * QK_BS + h * 96;
  const float* Kp = Kb + (size_t)b * QK_BS + h * 96;
  for (int i = tid; i < CQ * 96; i += TB) {
    int cq = i / 96, ww = i % 96;
    qr[cq][ww] = Qp[cq * NHW + ww];
    kr[cq][ww] = Kp[cq * NHW + ww];
  }
  if (tid < 96) {
    smv[tid] = mArr[((size_t)b * 96 + h) * 96 + tid];
    siv[tid] = invArr[((size_t)b * 96 + h) * 96 + tid];
  }
  __syncthreads();
  for (int idx = tid; idx < 9216; idx += TB) {
    int w_ = idx / 96, v = idx % 96;
    float e = 0.f;
#pragma unroll
    for (int cq = 0; cq < CQ; ++cq) e += qr[cq][w_] * kr[cq][v];
    aw[w_][v] = __expf(e - smv[w_]) * siv[w_];
  }
  const u16* vp = vW + (size_t)(b * 96 + h) * 96 * 256;
  for (int i = tid; i < 96 * 256; i += TB) ((u16*)vs)[i] = vp[i];
  __syncthreads();
  int ww = tid % 96, grp = tid / 96;
  float gam = gammaP[0];
  const u16* t2 = tmp2 + (size_t)(b * 96 + h) * 256 * 96;
  for (int c = grp * 64; c < grp * 64 + 64; ++c) {
    float acc = 0.f;
#pragma unroll 4
    for (int v = 0; v < 96; ++v) acc += bf2f(vs[v][c]) * aw[ww][v];
    size_t xoff = ((size_t)(b * Cn + c) * 96 + h) * 96 + ww;
    out[xoff] = x[xoff] + gam * (bf2f(t2[(size_t)c * 96 + ww]) + acc);
  }
}

extern "C" void kernel_launch(void* const* d_in, const int* in_sizes, int n_in,
                              void* d_out, int out_size, void* d_ws, size_t ws_size,
                              hipStream_t stream) {
  const float* x0 = (const float*)d_in[0];
  const float* x1 = (const float*)d_in[1];
  const float* wq0 = (const float*)d_in[2];
  const float* bq0 = (const float*)d_in[3];
  const float* wk0 = (const float*)d_in[4];
  const float* bk0 = (const float*)d_in[5];
  const float* wv0 = (const float*)d_in[6];
  const float* bv0 = (const float*)d_in[7];
  const float* wq1 = (const float*)d_in[8];
  const float* bq1 = (const float*)d_in[9];
  const float* wk1 = (const float*)d_in[10];
  const float* bk1 = (const float*)d_in[11];
  const float* wv1 = (const float*)d_in[12];
  const float* bv1 = (const float*)d_in[13];
  const float* gamma = (const float*)d_in[14];
  float* out = (float*)d_out;

  char* ws = (char*)d_ws;
  size_t off = 0;
  auto alloc = [&](size_t bytes) -> void* {
    void* p = ws + off;
    off += (bytes + 255) & ~(size_t)255;
    return p;
  };
  const size_t SZ_P = (size_t)Bn * QKC * NHW * 4;        // 18.9 MB
  const size_t SZ_V = (size_t)Bn * NHW * Cn * 2;         // 37.7 MB
  float* P0 = (float*)alloc(SZ_P);
  float* P1 = (float*)alloc(SZ_P);
  u16* vH0 = (u16*)alloc(SZ_V);
  u16* vW0 = (u16*)alloc(SZ_V);
  u16* vH1 = (u16*)alloc(SZ_V);
  u16* vW1 = (u16*)alloc(SZ_V);
  u16* tmp1 = (u16*)alloc(SZ_V);
  u16* tmp2 = (u16*)alloc(SZ_V);
  float* Wqk0 = (float*)alloc(64 * 256 * 4);
  float* Wqk1 = (float*)alloc(64 * 256 * 4);
  float* bqk0 = (float*)alloc(64 * 4);
  float* bqk1 = (float*)alloc(64 * 4);
  float* mA = (float*)alloc((size_t)Bn * NHW * 4);
  float* iA = (float*)alloc((size_t)Bn * NHW * 4);
  (void)ws_size; (void)in_sizes; (void)n_in; (void)out_size;

  pack_qk<<<64, 256, 0, stream>>>(wq0, bq0, wk0, bk0, Wqk0, bqk0);
  pack_qk<<<64, 256, 0, stream>>>(wq1, bq1, wk1, bk1, Wqk1, bqk1);

  dim3 gqk(144, 1, Bn), gv(144, 4, Bn);
  proj_gemm<0><<<gqk, 256, 0, stream>>>(x0, Wqk0, bqk0, P0, nullptr, nullptr, QKC);
  proj_gemm<0><<<gqk, 256, 0, stream>>>(x1, Wqk1, bqk1, P1, nullptr, nullptr, QKC);
  proj_gemm<1><<<gv, 256, 0, stream>>>(x0, wv0, bv0, nullptr, vH0, vW0, Cn);
  proj_gemm<1><<<gv, 256, 0, stream>>>(x1, wv1, bv1, nullptr, vH1, vW1, Cn);

  dim3 ga(Wn, Bn), gt(Cn, Bn);
  const float* K0 = P0 + 32 * NHW;  // k channels live at [32..64) of P
  const float* K1 = P1 + 32 * NHW;
  // cat0 = gamma * attend(q1, k0, v0) + x0
  attn_col<<<ga, TB, 0, stream>>>(P1, K0, vH0, mA, iA, tmp1);
  transpose_hw<<<gt, 256, 0, stream>>>(tmp1, tmp2);
  attn_row<<<ga, TB, 0, stream>>>(P1, K0, vW0, mA, iA, tmp2, x0, gamma, out);
  // cat1 = gamma * attend(q0, k1, v1) + x1
  attn_col<<<ga, TB, 0, stream>>>(P0, K1, vH1, mA, iA, tmp1);
  transpose_hw<<<gt, 256, 0, stream>>>(tmp1, tmp2);
  attn_row<<<ga, TB, 0, stream>>>(P0, K1, vW1, mA, iA, tmp2, x1, gamma,
                                  out + (size_t)Bn * Cn * NHW);
}

// Round 2
// 942.294 us; speedup vs baseline: 3.3654x; 3.3654x over previous
//
#include <hip/hip_runtime.h>
#include <hip/hip_bf16.h>

// CrissCross (axial) attention, B=8 C=256 H=W=96 CQ=32.
//  pack_qk     : concat wq|wk -> Wqk[64][256] per input
//  proj_gemm<0>: q,k fp32 planes P[b][64][9216]
//  proj_gemm<1>: v -> bf16 vW[b][h][c][w] (coalesced direct write)
//  vtrans      : vW -> vH[b][w][c][g]
//  attn_col    : per (b,w): logits in regs, softmax stats (m,1/s), MFMA apply -> tmp1[b][w][c][h]
//  transpose_hw: tmp1 -> tmp2[b][h][c][w]
//  attn_row    : per (b,h): e_w, MFMA apply, out = x + gamma*(out_h+out_w)

#define Bn 8
#define Cn 256
#define Hn 96
#define Wn 96
#define CQ 32
#define NHW 9216
#define QKC 64
#define QK_BS (QKC * NHW)

typedef unsigned short u16;
typedef __attribute__((ext_vector_type(8))) short bf16x8;
typedef __attribute__((ext_vector_type(4))) float f32x4;

__device__ __forceinline__ float bf2f(u16 v) {
  union { unsigned int u; float f; } x; x.u = ((unsigned int)v) << 16; return x.f;
}
__device__ __forceinline__ u16 f2bf(float f) {
  union { unsigned int u; float f; } x; x.f = f;
  unsigned int r = x.u + 0x7fff + ((x.u >> 16) & 1);
  return (u16)(r >> 16);
}

__global__ __launch_bounds__(256) void pack_qk(const float* __restrict__ wq, const float* __restrict__ bq,
                                               const float* __restrict__ wk, const float* __restrict__ bk,
                                               float* __restrict__ Wqk, float* __restrict__ bqk) {
  int i = blockIdx.x * 256 + threadIdx.x;
  if (i < 64 * 256) {
    int o = i >> 8, c = i & 255;
    Wqk[i] = (o < 32) ? wq[o * 256 + c] : wk[(o - 32) * 256 + c];
  }
  if (i < 64) bqk[i] = (i < 32) ? bq[i] : bk[i - 32];
}

// MODE 0: write fp32 Y[b][o][n].  MODE 1: write bf16 vW[b][h][c][w].
template <int MODE>
__global__ __launch_bounds__(256) void proj_gemm(const float* __restrict__ X, const float* __restrict__ Wm,
                                                 const float* __restrict__ bias, float* __restrict__ Y,
                                                 u16* __restrict__ vW, int Otot) {
  __shared__ float sW[16][68];
  __shared__ float sX[16][68];
  __shared__ u16 sO[64][72];
  int b = blockIdx.z;
  int o0 = blockIdx.y * 64;
  int n0 = blockIdx.x * 64;
  int tid = threadIdx.x;
  int tr = tid >> 4, tc = tid & 15;
  const float* Xb = X + (size_t)b * Cn * NHW;
  float acc[4][4] = {};
  for (int c0 = 0; c0 < Cn; c0 += 16) {
    for (int i = tid; i < 1024; i += 256) {
      int kk = i & 15, oo = i >> 4;
      sW[kk][oo] = Wm[(size_t)(o0 + oo) * Cn + c0 + kk];
    }
    for (int i = tid; i < 1024; i += 256) {
      int nn = i & 63, kk = i >> 6;
      sX[kk][nn] = Xb[(size_t)(c0 + kk) * NHW + n0 + nn];
    }
    __syncthreads();
#pragma unroll
    for (int kk = 0; kk < 16; ++kk) {
      float4 xv = *(const float4*)&sX[kk][tc * 4];
      float4 wv = *(const float4*)&sW[kk][tr * 4];
      float wa[4] = {wv.x, wv.y, wv.z, wv.w};
      float xa[4] = {xv.x, xv.y, xv.z, xv.w};
#pragma unroll
      for (int i = 0; i < 4; ++i)
#pragma unroll
        for (int j = 0; j < 4; ++j) acc[i][j] += wa[i] * xa[j];
    }
    __syncthreads();
  }
  if (MODE == 0) {
    float* Yb = Y + (size_t)b * Otot * NHW;
#pragma unroll
    for (int i = 0; i < 4; ++i) {
      int o = o0 + tr * 4 + i;
      float bv = bias[o];
      float4 r = make_float4(acc[i][0] + bv, acc[i][1] + bv, acc[i][2] + bv, acc[i][3] + bv);
      *(float4*)&Yb[(size_t)o * NHW + n0 + tc * 4] = r;
    }
  } else {
#pragma unroll
    for (int i = 0; i < 4; ++i) {
      float bv = bias[o0 + tr * 4 + i];
#pragma unroll
      for (int j = 0; j < 4; ++j) sO[tc * 4 + j][tr * 4 + i] = f2bf(acc[i][j] + bv);
    }
    __syncthreads();
    for (int idx = tid; idx < 4096; idx += 256) {
      int cc = idx >> 6, nn = idx & 63;
      int n = n0 + nn, ih = n / 96, jw = n % 96;
      vW[((size_t)(b * 96 + ih) * 256 + o0 + cc) * 96 + jw] = sO[nn][cc];
    }
  }
}

// vH[b][w][c][g] = vW[b][g][c][w] : per-(b,c) 96x96 transpose through LDS.
__global__ __launch_bounds__(256) void vtrans(const u16* __restrict__ vW, u16* __restrict__ vH) {
  __shared__ u16 t[96][98];
  const int c = blockIdx.x, b = blockIdx.y;
  for (int idx = threadIdx.x; idx < 4608; idx += 256) {
    int hh = idx / 48, w2 = idx % 48;
    *(unsigned int*)&t[hh][w2 * 2] =
        *(const unsigned int*)(vW + (size_t)(b * 96 + hh) * 24576 + c * 96 + w2 * 2);
  }
  __syncthreads();
  for (int idx = threadIdx.x; idx < 4608; idx += 256) {
    int ww = idx / 48, g2 = idx % 48;
    unsigned int lo = t[g2 * 2][ww];
    unsigned int hi = t[g2 * 2 + 1][ww];
    *(unsigned int*)(vH + (size_t)(b * 96 + ww) * 24576 + c * 96 + g2 * 2) = lo | (hi << 16);
  }
}

// Column pass, block (b,w): e_h (regs) + e_w (global k stream), full softmax stats,
// probs->bf16 LDS, MFMA apply out_h -> tmp1[b][w][c][h].
__global__ __launch_bounds__(384) void attn_col(const float* __restrict__ Qb, const float* __restrict__ Kb,
                                                const u16* __restrict__ vH, float* __restrict__ mArr,
                                                float* __restrict__ invArr, u16* __restrict__ tmp1) {
  __shared__ __align__(16) char smem[46592];
  float* qs = (float*)smem;               // [32][100]
  float* ks = (float*)(smem + 12800);     // [32][100]
  u16* vbuf = (u16*)smem;                 // [128][104], overlays qs/ks after logits
  u16* probs = (u16*)(smem + 26624);      // [96][104]
  const int w = blockIdx.x, b = blockIdx.y;
  const int tid = threadIdx.x;
  const float* Qp = Qb + (size_t)b * QK_BS;
  const float* Kp = Kb + (size_t)b * QK_BS;
  for (int i = tid; i < 3072; i += 384) {
    int cq = i / 96, hh = i % 96;
    qs[cq * 100 + hh] = Qp[(size_t)cq * NHW + hh * 96 + w];
    ks[cq * 100 + hh] = Kp[(size_t)cq * NHW + hh * 96 + w];
  }
  __syncthreads();
  const int h = tid >> 2, j = tid & 3;
  float eh[24], ew[24];
#pragma unroll
  for (int i = 0; i < 24; ++i) { eh[i] = 0.f; ew[i] = 0.f; }
  const float* kgl = Kp + (size_t)h * 96 + j * 24;
  for (int cq = 0; cq < 32; ++cq) {
    float qv = qs[cq * 100 + h];
    const float4* k4 = (const float4*)(ks + cq * 100 + j * 24);
    const float4* g4 = (const float4*)(kgl + (size_t)cq * NHW);
#pragma unroll
    for (int t4 = 0; t4 < 6; ++t4) {
      float4 a = k4[t4];
      float4 bb = g4[t4];
      eh[t4 * 4 + 0] += qv * a.x; eh[t4 * 4 + 1] += qv * a.y;
      eh[t4 * 4 + 2] += qv * a.z; eh[t4 * 4 + 3] += qv * a.w;
      ew[t4 * 4 + 0] += qv * bb.x; ew[t4 * 4 + 1] += qv * bb.y;
      ew[t4 * 4 + 2] += qv * bb.z; ew[t4 * 4 + 3] += qv * bb.w;
    }
  }
#pragma unroll
  for (int i = 0; i < 24; ++i)
    if (j * 24 + i == h) eh[i] = -1e30f;  // diagonal mask on e_h
  float mx = -1e30f;
#pragma unroll
  for (int i = 0; i < 24; ++i) mx = fmaxf(mx, fmaxf(eh[i], ew[i]));
  mx = fmaxf(mx, __shfl_xor(mx, 1));
  mx = fmaxf(mx, __shfl_xor(mx, 2));
  float s = 0.f;
#pragma unroll
  for (int i = 0; i < 24; ++i) {
    eh[i] = __expf(eh[i] - mx);
    s += eh[i] + __expf(ew[i] - mx);
  }
  s += __shfl_xor(s, 1);
  s += __shfl_xor(s, 2);
  float inv = 1.f / s;
  if (j == 0) {
    mArr[((size_t)b * 96 + h) * 96 + w] = mx;
    invArr[((size_t)b * 96 + h) * 96 + w] = inv;
  }
  unsigned int* prow = (unsigned int*)(probs + h * 104 + j * 24);
#pragma unroll
  for (int p2 = 0; p2 < 12; ++p2) {
    unsigned int lo = f2bf(eh[2 * p2] * inv);
    unsigned int hi = f2bf(eh[2 * p2 + 1] * inv);
    prow[p2] = lo | (hi << 16);
  }
  __syncthreads();
  // MFMA: D[h][c] = sum_g probs[h][g] * vH[c][g]
  const int lane = tid & 63, wv = tid >> 6;
  const int h0 = wv * 16;
  const int arow = h0 + (lane & 15);
  const int kc = (lane >> 4) * 8;
  bf16x8 af[3];
#pragma unroll
  for (int kt = 0; kt < 3; ++kt)
    af[kt] = *(const bf16x8*)(probs + arow * 104 + kt * 32 + kc);
  for (int half = 0; half < 2; ++half) {
    const u16* vp = vH + ((size_t)(b * 96 + w) * 256 + half * 128) * 96;
    for (int idx = tid; idx < 1536; idx += 384) {
      int r = idx / 12, c4 = idx % 12;
      *(float4*)(vbuf + r * 104 + c4 * 8) = *(const float4*)(vp + (size_t)r * 96 + c4 * 8);
    }
    __syncthreads();
    f32x4 acc[8];
#pragma unroll
    for (int nt = 0; nt < 8; ++nt) {
      f32x4 a = {0.f, 0.f, 0.f, 0.f};
#pragma unroll
      for (int kt = 0; kt < 3; ++kt) {
        bf16x8 bf = *(const bf16x8*)(vbuf + (nt * 16 + (lane & 15)) * 104 + kt * 32 + kc);
        a = __builtin_amdgcn_mfma_f32_16x16x32_bf16(af[kt], bf, a, 0, 0, 0);
      }
      acc[nt] = a;
    }
    __syncthreads();
#pragma unroll
    for (int nt = 0; nt < 8; ++nt) {
      int c2 = nt * 16 + (lane & 15);
      int hh = h0 + ((lane >> 4) << 2);
#pragma unroll
      for (int r = 0; r < 4; ++r) vbuf[c2 * 104 + hh + r] = f2bf(acc[nt][r]);
    }
    __syncthreads();
    u16* tp = tmp1 + ((size_t)(b * 96 + w) * 256 + half * 128) * 96;
    for (int idx = tid; idx < 1536; idx += 384) {
      int r = idx / 12, c4 = idx % 12;
      *(float4*)(tp + (size_t)r * 96 + c4 * 8) = *(const float4*)(vbuf + r * 104 + c4 * 8);
    }
    __syncthreads();
  }
}

__global__ __launch_bounds__(256) void transpose_hw(const u16* __restrict__ tmp1, u16* __restrict__ tmp2) {
  __shared__ u16 t[96][98];
  int c = blockIdx.x, b = blockIdx.y;
  int tid = threadIdx.x;
  for (int idx = tid; idx < 9216; idx += 256) {
    int w_ = idx / 96, hh = idx % 96;
    t[w_][hh] = tmp1[((size_t)(b * 96 + w_) * 256 + c) * 96 + hh];
  }
  __syncthreads();
  for (int idx = tid; idx < 9216; idx += 256) {
    int hh = idx / 96, w_ = idx % 96;
    tmp2[((size_t)(b * 96 + hh) * 256 + c) * 96 + w_] = t[w_][hh];
  }
}

// Row pass, block (b,h): e_w from LDS, stored stats, MFMA apply,
// out = x + gamma*(tmp2 + out_w), coalesced fp32 writes.
__global__ __launch_bounds__(384) void attn_row(const float* __restrict__ Qb, const float* __restrict__ Kb,
                                                const u16* __restrict__ vW, const float* __restrict__ mArr,
                                                const float* __restrict__ invArr, const u16* __restrict__ tmp2,
                                                const float* __restrict__ x, const float* __restrict__ gammaP,
                                                float* __restrict__ out) {
  __shared__ __align__(16) char smem[46592];
  float* qr = (float*)smem;               // [32][100]
  float* kr = (float*)(smem + 12800);     // [32][100]
  u16* vbuf = (u16*)smem;                 // [128][104]
  u16* probs = (u16*)(smem + 26624);      // [96][104]
  const int h = blockIdx.x, b = blockIdx.y;
  const int tid = threadIdx.x;
  const float* Qp = Qb + (size_t)b * QK_BS + h * 96;
  const float* Kp = Kb + (size_t)b * QK_BS + h * 96;
  for (int i = tid; i < 3072; i += 384) {
    int cq = i / 96, ww = i % 96;
    qr[cq * 100 + ww] = Qp[(size_t)cq * NHW + ww];
    kr[cq * 100 + ww] = Kp[(size_t)cq * NHW + ww];
  }
  __syncthreads();
  const int w_ = tid >> 2, j = tid & 3;
  float ev[24];
#pragma unroll
  for (int i = 0; i < 24; ++i) ev[i] = 0.f;
  for (int cq = 0; cq < 32; ++cq) {
    float qv = qr[cq * 100 + w_];
    const float4* k4 = (const float4*)(kr + cq * 100 + j * 24);
#pragma unroll
    for (int t4 = 0; t4 < 6; ++t4) {
      float4 a = k4[t4];
      ev[t4 * 4 + 0] += qv * a.x; ev[t4 * 4 + 1] += qv * a.y;
      ev[t4 * 4 + 2] += qv * a.z; ev[t4 * 4 + 3] += qv * a.w;
    }
  }
  float mx = mArr[((size_t)b * 96 + h) * 96 + w_];
  float inv = invArr[((size_t)b * 96 + h) * 96 + w_];
  unsigned int* prow = (unsigned int*)(probs + w_ * 104 + j * 24);
#pragma unroll
  for (int p2 = 0; p2 < 12; ++p2) {
    unsigned int lo = f2bf(__expf(ev[2 * p2] - mx) * inv);
    unsigned int hi = f2bf(__expf(ev[2 * p2 + 1] - mx) * inv);
    prow[p2] = lo | (hi << 16);
  }
  __syncthreads();
  const int lane = tid & 63, wv = tid >> 6;
  const int w0 = wv * 16;
  const int arow = w0 + (lane & 15);
  const int kc = (lane >> 4) * 8;
  bf16x8 af[3];
#pragma unroll
  for (int kt = 0; kt < 3; ++kt)
    af[kt] = *(const bf16x8*)(probs + arow * 104 + kt * 32 + kc);
  const float gam = gammaP[0];
  const u16* t2b = tmp2 + (size_t)(b * 96 + h) * 24576;
  for (int half = 0; half < 2; ++half) {
    const u16* vp = vW + ((size_t)(b * 96 + h) * 256 + half * 128) * 96;
    for (int idx = tid; idx < 1536; idx += 384) {
      int r = idx / 12, c4 = idx % 12;
      *(float4*)(vbuf + r * 104 + c4 * 8) = *(const float4*)(vp + (size_t)r * 96 + c4 * 8);
    }
    __syncthreads();
    f32x4 acc[8];
#pragma unroll
    for (int nt = 0; nt < 8; ++nt) {
      f32x4 a = {0.f, 0.f, 0.f, 0.f};
#pragma unroll
      for (int kt = 0; kt < 3; ++kt) {
        bf16x8 bf = *(const bf16x8*)(vbuf + (nt * 16 + (lane & 15)) * 104 + kt * 32 + kc);
        a = __builtin_amdgcn_mfma_f32_16x16x32_bf16(af[kt], bf, a, 0, 0, 0);
      }
      acc[nt] = a;
    }
    __syncthreads();
#pragma unroll
    for (int nt = 0; nt < 8; ++nt) {
      int c2 = nt * 16 + (lane & 15);
      int ww0 = w0 + ((lane >> 4) << 2);
#pragma unroll
      for (int r = 0; r < 4; ++r) vbuf[c2 * 104 + ww0 + r] = f2bf(acc[nt][r]);
    }
    __syncthreads();
    for (int idx = tid; idx < 3072; idx += 384) {
      int r = idx / 24, w4 = idx % 24;
      int c = half * 128 + r;
      size_t go = ((size_t)(b * 256 + c) * 96 + h) * 96 + w4 * 4;
      float4 xv = *(const float4*)(x + go);
      ushort4 tv = *(const ushort4*)(t2b + (size_t)c * 96 + w4 * 4);
      ushort4 dv = *(const ushort4*)(vbuf + r * 104 + w4 * 4);
      float4 ov;
      ov.x = xv.x + gam * (bf2f(tv.x) + bf2f(dv.x));
      ov.y = xv.y + gam * (bf2f(tv.y) + bf2f(dv.y));
      ov.z = xv.z + gam * (bf2f(tv.z) + bf2f(dv.z));
      ov.w = xv.w + gam * (bf2f(tv.w) + bf2f(dv.w));
      *(float4*)(out + go) = ov;
    }
    __syncthreads();
  }
}

extern "C" void kernel_launch(void* const* d_in, const int* in_sizes, int n_in,
                              void* d_out, int out_size, void* d_ws, size_t ws_size,
                              hipStream_t stream) {
  const float* x0 = (const float*)d_in[0];
  const float* x1 = (const float*)d_in[1];
  const float* wq0 = (const float*)d_in[2];
  const float* bq0 = (const float*)d_in[3];
  const float* wk0 = (const float*)d_in[4];
  const float* bk0 = (const float*)d_in[5];
  const float* wv0 = (const float*)d_in[6];
  const float* bv0 = (const float*)d_in[7];
  const float* wq1 = (const float*)d_in[8];
  const float* bq1 = (const float*)d_in[9];
  const float* wk1 = (const float*)d_in[10];
  const float* bk1 = (const float*)d_in[11];
  const float* wv1 = (const float*)d_in[12];
  const float* bv1 = (const float*)d_in[13];
  const float* gamma = (const float*)d_in[14];
  float* out = (float*)d_out;

  char* ws = (char*)d_ws;
  size_t off = 0;
  auto alloc = [&](size_t bytes) -> void* {
    void* p = ws + off;
    off += (bytes + 255) & ~(size_t)255;
    return p;
  };
  const size_t SZ_P = (size_t)Bn * QKC * NHW * 4;  // 18.9 MB
  const size_t SZ_V = (size_t)Bn * NHW * Cn * 2;   // 37.7 MB
  float* P0 = (float*)alloc(SZ_P);
  float* P1 = (float*)alloc(SZ_P);
  u16* vW0 = (u16*)alloc(SZ_V);
  u16* vH0 = (u16*)alloc(SZ_V);
  u16* vW1 = (u16*)alloc(SZ_V);
  u16* vH1 = (u16*)alloc(SZ_V);
  u16* tmp1 = (u16*)alloc(SZ_V);
  u16* tmp2 = (u16*)alloc(SZ_V);
  float* Wqk0 = (float*)alloc(64 * 256 * 4);
  float* Wqk1 = (float*)alloc(64 * 256 * 4);
  float* bqk0 = (float*)alloc(64 * 4);
  float* bqk1 = (float*)alloc(64 * 4);
  float* mA = (float*)alloc((size_t)Bn * NHW * 4);
  float* iA = (float*)alloc((size_t)Bn * NHW * 4);
  (void)ws_size; (void)in_sizes; (void)n_in; (void)out_size;

  pack_qk<<<64, 256, 0, stream>>>(wq0, bq0, wk0, bk0, Wqk0, bqk0);
  pack_qk<<<64, 256, 0, stream>>>(wq1, bq1, wk1, bk1, Wqk1, bqk1);

  dim3 gqk(144, 1, Bn), gv(144, 4, Bn);
  proj_gemm<0><<<gqk, 256, 0, stream>>>(x0, Wqk0, bqk0, P0, nullptr, QKC);
  proj_gemm<0><<<gqk, 256, 0, stream>>>(x1, Wqk1, bqk1, P1, nullptr, QKC);
  proj_gemm<1><<<gv, 256, 0, stream>>>(x0, wv0, bv0, nullptr, vW0, Cn);
  proj_gemm<1><<<gv, 256, 0, stream>>>(x1, wv1, bv1, nullptr, vW1, Cn);

  dim3 gt(Cn, Bn);
  vtrans<<<gt, 256, 0, stream>>>(vW0, vH0);
  vtrans<<<gt, 256, 0, stream>>>(vW1, vH1);

  dim3 ga(Wn, Bn);
  const float* K0 = P0 + 32 * NHW;
  const float* K1 = P1 + 32 * NHW;
  // cat0 = gamma * attend(q1, k0, v0) + x0
  attn_col<<<ga, 384, 0, stream>>>(P1, K0, vH0, mA, iA, tmp1);
  transpose_hw<<<gt, 256, 0, stream>>>(tmp1, tmp2);
  attn_row<<<ga, 384, 0, stream>>>(P1, K0, vW0, mA, iA, tmp2, x0, gamma, out);
  // cat1 = gamma * attend(q0, k1, v1) + x1
  attn_col<<<ga, 384, 0, stream>>>(P0, K1, vH1, mA, iA, tmp1);
  transpose_hw<<<gt, 256, 0, stream>>>(tmp1, tmp2);
  attn_row<<<ga, 384, 0, stream>>>(P0, K1, vW1, mA, iA, tmp2, x1, gamma,
                                   out + (size_t)Bn * Cn * NHW);
}

// Round 3
// 530.515 us; speedup vs baseline: 5.9776x; 1.7762x over previous
//
#include <hip/hip_runtime.h>
#include <hip/hip_bf16.h>

// CrissCross attention, B=8 C=256 H=W=96 CQ=32. Flash-style split softmax:
//  pack_qk : Wqk[64][256] fp32 per input;  pack_wv: wv -> bf16
//  proj_qk : q,k -> Pt[b][n][64] fp32 (n-major)
//  vproj   : MFMA bf16 v-projection -> vW[b][h][c][w]
//  vtrans  : vW -> vH[b][w][c][g]
//  attn<0> : per (b,h): e_w once, local stats (mW,sW), out_w'=sum e^(e-m) V -> tmpW[b][h][c][w]
//  attn<1> : per (b,w): e_h (diag mask), stats (mH,sH), out_h' -> tmpH[b][w][c][h]
//  scl     : exact concat-softmax rescale factors sclH/sclW[b][h][w] (gamma folded)
//  tkomb   : out = x + tmpH^T*sclH + tmpW*sclW  (transpose fused)

#define Bn 8
#define Cn 256
#define NHW 9216

typedef unsigned short u16;
typedef __attribute__((ext_vector_type(8))) short bf16x8;
typedef __attribute__((ext_vector_type(4))) float f32x4;

__device__ __forceinline__ float bf2f(u16 v) {
  union { unsigned int u; float f; } x; x.u = ((unsigned int)v) << 16; return x.f;
}
__device__ __forceinline__ u16 f2bf(float f) {
  union { unsigned int u; float f; } x; x.f = f;
  unsigned int r = x.u + 0x7fff + ((x.u >> 16) & 1);
  return (u16)(r >> 16);
}

__global__ __launch_bounds__(256) void pack_qk(const float* __restrict__ wq, const float* __restrict__ bq,
                                               const float* __restrict__ wk, const float* __restrict__ bk,
                                               float* __restrict__ Wqk, float* __restrict__ bqk) {
  int i = blockIdx.x * 256 + threadIdx.x;
  if (i < 64 * 256) {
    int o = i >> 8, c = i & 255;
    Wqk[i] = (o < 32) ? wq[o * 256 + c] : wk[(o - 32) * 256 + c];
  }
  if (i < 64) bqk[i] = (i < 32) ? bq[i] : bk[i - 32];
}

__global__ __launch_bounds__(256) void pack_wv(const float* __restrict__ wv, u16* __restrict__ Wvb) {
  int i = blockIdx.x * 256 + threadIdx.x;
  if (i < 65536) Wvb[i] = f2bf(wv[i]);
}

// q,k projection (fp32 VALU GEMM), output n-major Pt[b][n][64].
__global__ __launch_bounds__(256) void proj_qk(const float* __restrict__ X, const float* __restrict__ Wm,
                                               const float* __restrict__ bias, float* __restrict__ Pt) {
  __shared__ float sW[16][68];
  __shared__ float sX[16][68];
  int b = blockIdx.y;
  int n0 = blockIdx.x * 64;
  int tid = threadIdx.x;
  int tr = tid >> 4, tc = tid & 15;
  const float* Xb = X + (size_t)b * Cn * NHW;
  float acc[4][4] = {};
  for (int c0 = 0; c0 < Cn; c0 += 16) {
    for (int i = tid; i < 1024; i += 256) {
      int kk = i & 15, oo = i >> 4;
      sW[kk][oo] = Wm[(size_t)oo * Cn + c0 + kk];
    }
    for (int i = tid; i < 1024; i += 256) {
      int nn = i & 63, kk = i >> 6;
      sX[kk][nn] = Xb[(size_t)(c0 + kk) * NHW + n0 + nn];
    }
    __syncthreads();
#pragma unroll
    for (int kk = 0; kk < 16; ++kk) {
      float4 xv = *(const float4*)&sX[kk][tc * 4];
      float4 wv = *(const float4*)&sW[kk][tr * 4];
      float wa[4] = {wv.x, wv.y, wv.z, wv.w};
      float xa[4] = {xv.x, xv.y, xv.z, xv.w};
#pragma unroll
      for (int i = 0; i < 4; ++i)
#pragma unroll
        for (int j = 0; j < 4; ++j) acc[i][j] += wa[i] * xa[j];
    }
    __syncthreads();
  }
  float4 bv = *(const float4*)(bias + tr * 4);
  float* Pb = Pt + (size_t)b * 589824;
#pragma unroll
  for (int j = 0; j < 4; ++j) {
    float4 r = make_float4(acc[0][j] + bv.x, acc[1][j] + bv.y, acc[2][j] + bv.z, acc[3][j] + bv.w);
    *(float4*)&Pb[(size_t)(n0 + tc * 4 + j) * 64 + tr * 4] = r;
  }
}

// v projection, MFMA bf16: block (h, b), M=256 c_out, N=96 (one h-row), K=256.
__global__ __launch_bounds__(256, 3) void vproj(const float* __restrict__ X, const u16* __restrict__ Wvb,
                                                const float* __restrict__ bias, u16* __restrict__ vW) {
  __shared__ u16 xs[96][264];  // bf16 x-tile, [n][cin], 50688 B
  u16* sO = &xs[0][0];         // overlay: [64][104] for epilogue
  const int h = blockIdx.x, b = blockIdx.y;
  const int tid = threadIdx.x;
  const float* Xb = X + (size_t)b * Cn * NHW + h * 96;
  for (int idx = tid; idx < 6144; idx += 256) {
    int cin = idx / 24, n4 = idx % 24;
    float4 v = *(const float4*)(Xb + (size_t)cin * NHW + n4 * 4);
    xs[n4 * 4 + 0][cin] = f2bf(v.x);
    xs[n4 * 4 + 1][cin] = f2bf(v.y);
    xs[n4 * 4 + 2][cin] = f2bf(v.z);
    xs[n4 * 4 + 3][cin] = f2bf(v.w);
  }
  __syncthreads();
  const int lane = tid & 63, wv = tid >> 6;
  const int kc = (lane >> 4) * 8;
  f32x4 acc[4][6] = {};
#pragma unroll
  for (int kk = 0; kk < 8; ++kk) {
    bf16x8 a4[4], b6[6];
#pragma unroll
    for (int mi = 0; mi < 4; ++mi)
      a4[mi] = *(const bf16x8*)(Wvb + (size_t)(wv * 64 + mi * 16 + (lane & 15)) * 256 + kk * 32 + kc);
#pragma unroll
    for (int nt = 0; nt < 6; ++nt)
      b6[nt] = *(const bf16x8*)&xs[nt * 16 + (lane & 15)][kk * 32 + kc];
#pragma unroll
    for (int mi = 0; mi < 4; ++mi)
#pragma unroll
      for (int nt = 0; nt < 6; ++nt)
        acc[mi][nt] = __builtin_amdgcn_mfma_f32_16x16x32_bf16(a4[mi], b6[nt], acc[mi][nt], 0, 0, 0);
  }
  __syncthreads();
  for (int r = 0; r < 4; ++r) {
    if (wv == r) {
#pragma unroll
      for (int mi = 0; mi < 4; ++mi) {
        float4 bv = *(const float4*)(bias + r * 64 + mi * 16 + ((lane >> 4) << 2));
        float ba[4] = {bv.x, bv.y, bv.z, bv.w};
#pragma unroll
        for (int nt = 0; nt < 6; ++nt) {
          int col = nt * 16 + (lane & 15);
#pragma unroll
          for (int rr = 0; rr < 4; ++rr) {
            int lrow = mi * 16 + ((lane >> 4) << 2) + rr;
            sO[lrow * 104 + col] = f2bf(acc[mi][nt][rr] + ba[rr]);
          }
        }
      }
    }
    __syncthreads();
    for (int idx = tid; idx < 768; idx += 256) {
      int cc = idx / 12, c4 = idx % 12;
      *(float4*)(vW + ((size_t)(b * 96 + h) * 256 + r * 64 + cc) * 96 + c4 * 8) =
          *(const float4*)&sO[cc * 104 + c4 * 8];
    }
    __syncthreads();
  }
}

// vH[b][w][c][g] = vW[b][g][c][w]
__global__ __launch_bounds__(256) void vtrans(const u16* __restrict__ vW, u16* __restrict__ vH) {
  __shared__ u16 t[96][98];
  const int c = blockIdx.x, b = blockIdx.y;
  for (int idx = threadIdx.x; idx < 4608; idx += 256) {
    int hh = idx / 48, w2 = idx % 48;
    *(unsigned int*)&t[hh][w2 * 2] =
        *(const unsigned int*)(vW + (size_t)(b * 96 + hh) * 24576 + c * 96 + w2 * 2);
  }
  __syncthreads();
  for (int idx = threadIdx.x; idx < 4608; idx += 256) {
    int ww = idx / 48, g2 = idx % 48;
    unsigned int lo = t[g2 * 2][ww];
    unsigned int hi = t[g2 * 2 + 1][ww];
    *(unsigned int*)(vH + (size_t)(b * 96 + ww) * 24576 + c * 96 + g2 * 2) = lo | (hi << 16);
  }
}

// ISH=0: block (b,h) over e_w; ISH=1: block (b,w) over e_h (diag-masked).
// Computes logits once, local stats, unnormalized probs' = e^(e-m) -> MFMA apply -> tOut.
template <int ISH>
__global__ __launch_bounds__(384, 3) void attn_pass(const float* __restrict__ Qpt, const float* __restrict__ Kpt,
                                                    const u16* __restrict__ Vp, float* __restrict__ mOut,
                                                    float* __restrict__ sOut, u16* __restrict__ tOut) {
  __shared__ float qs[32][100];
  __shared__ float ks[32][100];
  __shared__ u16 probs[96][104];
  __shared__ u16 vbuf[128][104];
  const int p = blockIdx.x, b = blockIdx.y;
  const int tid = threadIdx.x;
  const size_t pbase = (size_t)b * 589824 + (size_t)(ISH ? p : p * 96) * 64;
  const int rstride = ISH ? 6144 : 64;
  for (int idx = tid; idx < 1536; idx += 384) {
    int i = idx >> 4, c4 = idx & 15;
    const float* src = (c4 < 8 ? Qpt : Kpt) + pbase + (size_t)i * rstride + c4 * 4;
    float4 v = *(const float4*)src;
    float* dst = (c4 < 8) ? &qs[c4 * 4][i] : &ks[(c4 - 8) * 4][i];
    dst[0] = v.x; dst[100] = v.y; dst[200] = v.z; dst[300] = v.w;
  }
  __syncthreads();
  const int row_ = tid >> 2, j = tid & 3;
  float e[24];
#pragma unroll
  for (int t = 0; t < 24; ++t) e[t] = 0.f;
  for (int cq = 0; cq < 32; ++cq) {
    float qv = qs[cq][row_];
    const float4* k4 = (const float4*)&ks[cq][j * 24];
#pragma unroll
    for (int t4 = 0; t4 < 6; ++t4) {
      float4 kk = k4[t4];
      e[t4 * 4 + 0] += qv * kk.x; e[t4 * 4 + 1] += qv * kk.y;
      e[t4 * 4 + 2] += qv * kk.z; e[t4 * 4 + 3] += qv * kk.w;
    }
  }
  if (ISH) {
#pragma unroll
    for (int t = 0; t < 24; ++t)
      if (j * 24 + t == row_) e[t] = -1e30f;
  }
  float mx = -1e30f;
#pragma unroll
  for (int t = 0; t < 24; ++t) mx = fmaxf(mx, e[t]);
  mx = fmaxf(mx, __shfl_xor(mx, 1));
  mx = fmaxf(mx, __shfl_xor(mx, 2));
  float s = 0.f;
#pragma unroll
  for (int t = 0; t < 24; ++t) {
    float pv = __expf(e[t] - mx);
    e[t] = pv; s += pv;
  }
  s += __shfl_xor(s, 1);
  s += __shfl_xor(s, 2);
  if (j == 0) {
    size_t sidx = ISH ? ((size_t)(b * 96 + row_) * 96 + p) : ((size_t)(b * 96 + p) * 96 + row_);
    mOut[sidx] = mx; sOut[sidx] = s;
  }
  unsigned int* prow = (unsigned int*)&probs[row_][j * 24];
#pragma unroll
  for (int p2 = 0; p2 < 12; ++p2) {
    unsigned int lo = f2bf(e[2 * p2]), hi = f2bf(e[2 * p2 + 1]);
    prow[p2] = lo | (hi << 16);
  }
  __syncthreads();
  const int lane = tid & 63, wv = tid >> 6;
  const int w0 = wv * 16;
  const int kc = (lane >> 4) * 8;
  bf16x8 af[3];
#pragma unroll
  for (int kt = 0; kt < 3; ++kt)
    af[kt] = *(const bf16x8*)&probs[w0 + (lane & 15)][kt * 32 + kc];
  const size_t vbase = (size_t)(b * 96 + p) * 24576;
  for (int half = 0; half < 2; ++half) {
    for (int idx = tid; idx < 1536; idx += 384) {
      int r = idx / 12, c4 = idx % 12;
      *(float4*)&vbuf[r][c4 * 8] = *(const float4*)(Vp + vbase + (size_t)(half * 128 + r) * 96 + c4 * 8);
    }
    __syncthreads();
    f32x4 acc[8];
#pragma unroll
    for (int nt = 0; nt < 8; ++nt) {
      f32x4 a = {0.f, 0.f, 0.f, 0.f};
#pragma unroll
      for (int kt = 0; kt < 3; ++kt) {
        bf16x8 bf = *(const bf16x8*)&vbuf[nt * 16 + (lane & 15)][kt * 32 + kc];
        a = __builtin_amdgcn_mfma_f32_16x16x32_bf16(af[kt], bf, a, 0, 0, 0);
      }
      acc[nt] = a;
    }
    __syncthreads();
#pragma unroll
    for (int nt = 0; nt < 8; ++nt) {
      int c2 = nt * 16 + (lane & 15);
      int wr = w0 + ((lane >> 4) << 2);
#pragma unroll
      for (int r = 0; r < 4; ++r) vbuf[c2][wr + r] = f2bf(acc[nt][r]);
    }
    __syncthreads();
    for (int idx = tid; idx < 1536; idx += 384) {
      int r = idx / 12, c4 = idx % 12;
      *(float4*)(tOut + vbase + (size_t)(half * 128 + r) * 96 + c4 * 8) = *(const float4*)&vbuf[r][c4 * 8];
    }
    __syncthreads();
  }
}

// Exact concat-softmax rescale: m=max(mh,mw), s=sh*e^(mh-m)+sw*e^(mw-m); scl*=gamma/s.
__global__ __launch_bounds__(256) void scl_k(const float* __restrict__ mH, const float* __restrict__ sH,
                                             const float* __restrict__ mW, const float* __restrict__ sW,
                                             const float* __restrict__ gammaP, float* __restrict__ sclH,
                                             float* __restrict__ sclW) {
  int i = blockIdx.x * 256 + threadIdx.x;
  if (i >= Bn * 9216) return;
  float mh = mH[i], mw = mW[i];
  float m = fmaxf(mh, mw);
  float eh = __expf(mh - m), ew = __expf(mw - m);
  float s = sH[i] * eh + sW[i] * ew;
  float g = gammaP[0] / s;
  sclH[i] = g * eh;
  sclW[i] = g * ew;
}

// Fused transpose + combine: out[b][c][h][w] = x + tmpH[b][w][c][h]*sclH[h][w] + tmpW[b][h][c][w]*sclW[h][w]
__global__ __launch_bounds__(256) void tkomb(const u16* __restrict__ tmpH, const u16* __restrict__ tmpW,
                                             const float* __restrict__ x, const float* __restrict__ sclH,
                                             const float* __restrict__ sclW, float* __restrict__ out) {
  __shared__ u16 t[96][108];
  const int c = blockIdx.x, b = blockIdx.y;
  const int tid = threadIdx.x;
  for (int idx = tid; idx < 2304; idx += 256) {
    int w_ = idx / 24, h4 = idx % 24;
    *(ushort4*)&t[w_][h4 * 4] =
        *(const ushort4*)(tmpH + ((size_t)(b * 96 + w_) * 256 + c) * 96 + h4 * 4);
  }
  __syncthreads();
  for (int idx = tid; idx < 2304; idx += 256) {
    int h_ = idx / 24, w4 = idx % 24;
    size_t go = ((size_t)(b * 256 + c) * 96 + h_) * 96 + w4 * 4;
    float4 xv = *(const float4*)(x + go);
    ushort4 wvv = *(const ushort4*)(tmpW + ((size_t)(b * 96 + h_) * 256 + c) * 96 + w4 * 4);
    float4 sh4 = *(const float4*)(sclH + (size_t)(b * 96 + h_) * 96 + w4 * 4);
    float4 sw4 = *(const float4*)(sclW + (size_t)(b * 96 + h_) * 96 + w4 * 4);
    float4 ov;
    ov.x = xv.x + bf2f(t[w4 * 4 + 0][h_]) * sh4.x + bf2f(wvv.x) * sw4.x;
    ov.y = xv.y + bf2f(t[w4 * 4 + 1][h_]) * sh4.y + bf2f(wvv.y) * sw4.y;
    ov.z = xv.z + bf2f(t[w4 * 4 + 2][h_]) * sh4.z + bf2f(wvv.z) * sw4.z;
    ov.w = xv.w + bf2f(t[w4 * 4 + 3][h_]) * sh4.w + bf2f(wvv.w) * sw4.w;
    *(float4*)(out + go) = ov;
  }
}

extern "C" void kernel_launch(void* const* d_in, const int* in_sizes, int n_in,
                              void* d_out, int out_size, void* d_ws, size_t ws_size,
                              hipStream_t stream) {
  const float* x0 = (const float*)d_in[0];
  const float* x1 = (const float*)d_in[1];
  const float* wq0 = (const float*)d_in[2];
  const float* bq0 = (const float*)d_in[3];
  const float* wk0 = (const float*)d_in[4];
  const float* bk0 = (const float*)d_in[5];
  const float* wv0 = (const float*)d_in[6];
  const float* bv0 = (const float*)d_in[7];
  const float* wq1 = (const float*)d_in[8];
  const float* bq1 = (const float*)d_in[9];
  const float* wk1 = (const float*)d_in[10];
  const float* bk1 = (const float*)d_in[11];
  const float* wv1 = (const float*)d_in[12];
  const float* bv1 = (const float*)d_in[13];
  const float* gamma = (const float*)d_in[14];
  float* out = (float*)d_out;

  char* ws = (char*)d_ws;
  size_t off = 0;
  auto alloc = [&](size_t bytes) -> void* {
    void* ptr = ws + off;
    off += (bytes + 255) & ~(size_t)255;
    return ptr;
  };
  const size_t SZ_P = (size_t)Bn * NHW * 64 * 4;   // 18.9 MB
  const size_t SZ_V = (size_t)Bn * NHW * Cn * 2;   // 37.7 MB
  const size_t SZ_S = (size_t)Bn * 9216 * 4;       // 294 KB
  float* Pt0 = (float*)alloc(SZ_P);
  float* Pt1 = (float*)alloc(SZ_P);
  u16* vW = (u16*)alloc(SZ_V);
  u16* vH = (u16*)alloc(SZ_V);
  u16* tmpW = (u16*)alloc(SZ_V);
  u16* tmpH = (u16*)alloc(SZ_V);
  float* Wqk0 = (float*)alloc(64 * 256 * 4);
  float* Wqk1 = (float*)alloc(64 * 256 * 4);
  float* bqk0 = (float*)alloc(64 * 4);
  float* bqk1 = (float*)alloc(64 * 4);
  u16* Wvb0 = (u16*)alloc(65536 * 2);
  u16* Wvb1 = (u16*)alloc(65536 * 2);
  float* mH = (float*)alloc(SZ_S);
  float* sH = (float*)alloc(SZ_S);
  float* mW = (float*)alloc(SZ_S);
  float* sW = (float*)alloc(SZ_S);
  float* sclH = (float*)alloc(SZ_S);
  float* sclW = (float*)alloc(SZ_S);
  (void)ws_size; (void)in_sizes; (void)n_in; (void)out_size;

  pack_qk<<<64, 256, 0, stream>>>(wq0, bq0, wk0, bk0, Wqk0, bqk0);
  pack_qk<<<64, 256, 0, stream>>>(wq1, bq1, wk1, bk1, Wqk1, bqk1);
  pack_wv<<<256, 256, 0, stream>>>(wv0, Wvb0);
  pack_wv<<<256, 256, 0, stream>>>(wv1, Wvb1);

  dim3 gqk(144, Bn), gp(96, Bn), gc(256, Bn);
  proj_qk<<<gqk, 256, 0, stream>>>(x0, Wqk0, bqk0, Pt0);
  proj_qk<<<gqk, 256, 0, stream>>>(x1, Wqk1, bqk1, Pt1);

  // pair 0: cat0 = gamma * attend(q1, k0, v0) + x0
  vproj<<<gp, 256, 0, stream>>>(x0, Wvb0, bv0, vW);
  vtrans<<<gc, 256, 0, stream>>>(vW, vH);
  attn_pass<0><<<gp, 384, 0, stream>>>(Pt1, Pt0, vW, mW, sW, tmpW);
  attn_pass<1><<<gp, 384, 0, stream>>>(Pt1, Pt0, vH, mH, sH, tmpH);
  scl_k<<<288, 256, 0, stream>>>(mH, sH, mW, sW, gamma, sclH, sclW);
  tkomb<<<gc, 256, 0, stream>>>(tmpH, tmpW, x0, sclH, sclW, out);

  // pair 1: cat1 = gamma * attend(q0, k1, v1) + x1
  vproj<<<gp, 256, 0, stream>>>(x1, Wvb1, bv1, vW);
  vtrans<<<gc, 256, 0, stream>>>(vW, vH);
  attn_pass<0><<<gp, 384, 0, stream>>>(Pt0, Pt1, vW, mW, sW, tmpW);
  attn_pass<1><<<gp, 384, 0, stream>>>(Pt0, Pt1, vH, mH, sH, tmpH);
  scl_k<<<288, 256, 0, stream>>>(mH, sH, mW, sW, gamma, sclH, sclW);
  tkomb<<<gc, 256, 0, stream>>>(tmpH, tmpW, x1, sclH, sclW, out + (size_t)Bn * Cn * NHW);
}

// Round 4
// 402.957 us; speedup vs baseline: 7.8699x; 1.3166x over previous
//
#include <hip/hip_runtime.h>
#include <hip/hip_bf16.h>

// CrissCross attention, B=8 C=256 H=W=96 CQ=32. Flash-style split softmax:
//  pack_all : [wq|wk|wv] -> bf16 Wall[320][256] + fp32 ball[320] per input
//  proj_all : one bf16-MFMA pass, block (h,b): x row-tile staged once ->
//             q,k fp32 Pt[b][n][64] (n-major) + v bf16 vW[b][h][c][w]
//  vtrans   : vW -> vH[b][w][c][g]
//  attn<0>  : per (b,h): e_w once, local stats (mW,sW), out_w' -> tmpW[b][h][c][w]
//  attn<1>  : per (b,w): e_h (diag mask), stats (mH,sH), out_h' -> tmpH[b][w][c][h]
//  scl      : exact concat-softmax rescale sclH/sclW[b][h][w] (gamma folded)
//  tkomb    : out = x + tmpH^T*sclH + tmpW*sclW (transpose fused)

#define Bn 8
#define Cn 256
#define NHW 9216

typedef unsigned short u16;
typedef __attribute__((ext_vector_type(8))) short bf16x8;
typedef __attribute__((ext_vector_type(4))) float f32x4;

__device__ __forceinline__ float bf2f(u16 v) {
  union { unsigned int u; float f; } x; x.u = ((unsigned int)v) << 16; return x.f;
}
__device__ __forceinline__ u16 f2bf(float f) {
  union { unsigned int u; float f; } x; x.f = f;
  unsigned int r = x.u + 0x7fff + ((x.u >> 16) & 1);
  return (u16)(r >> 16);
}

__global__ __launch_bounds__(256) void pack_all(const float* __restrict__ wq, const float* __restrict__ bq,
                                                const float* __restrict__ wk, const float* __restrict__ bk,
                                                const float* __restrict__ wv, const float* __restrict__ bv,
                                                u16* __restrict__ Wall, float* __restrict__ ball) {
  int i = blockIdx.x * 256 + threadIdx.x;
  if (i < 320 * 256) {
    int o = i >> 8, c = i & 255;
    float v = (o < 32) ? wq[o * 256 + c] : (o < 64) ? wk[(o - 32) * 256 + c] : wv[(o - 64) * 256 + c];
    Wall[i] = f2bf(v);
  }
  if (i < 320) ball[i] = (i < 32) ? bq[i] : (i < 64) ? bk[i - 32] : bv[i - 64];
}

// Fused projection: block (h, b). M=320 outputs, N=96 (one h-row), K=256, bf16 MFMA.
// Wave w owns m-tiles {w, w+4, w+8, w+12, w+16}: first = qk, rest = v.
__global__ __launch_bounds__(256, 2) void proj_all(const float* __restrict__ X, const u16* __restrict__ Wall,
                                                   const float* __restrict__ ball, float* __restrict__ Pt,
                                                   u16* __restrict__ vW) {
  __shared__ u16 xs[96][264];  // bf16 x-tile [n][cin], 50688 B
  u16* sO = &xs[0][0];         // overlay [64][104] for v epilogue
  const int h = blockIdx.x, b = blockIdx.y;
  const int tid = threadIdx.x;
  const float* Xb = X + (size_t)b * Cn * NHW + h * 96;
  for (int idx = tid; idx < 6144; idx += 256) {
    int cin = idx / 24, n4 = idx % 24;
    float4 v = *(const float4*)(Xb + (size_t)cin * NHW + n4 * 4);
    xs[n4 * 4 + 0][cin] = f2bf(v.x);
    xs[n4 * 4 + 1][cin] = f2bf(v.y);
    xs[n4 * 4 + 2][cin] = f2bf(v.z);
    xs[n4 * 4 + 3][cin] = f2bf(v.w);
  }
  __syncthreads();
  const int lane = tid & 63, wv = tid >> 6;
  const int arow = lane & 15;
  const int kc = (lane >> 4) * 8;
  f32x4 acc[5][6] = {};
#pragma unroll
  for (int kk = 0; kk < 8; ++kk) {
    bf16x8 a5[5], b6[6];
#pragma unroll
    for (int j = 0; j < 5; ++j)
      a5[j] = *(const bf16x8*)(Wall + (size_t)((wv + 4 * j) * 16 + arow) * 256 + kk * 32 + kc);
#pragma unroll
    for (int nt = 0; nt < 6; ++nt)
      b6[nt] = *(const bf16x8*)&xs[nt * 16 + arow][kk * 32 + kc];
#pragma unroll
    for (int j = 0; j < 5; ++j)
#pragma unroll
      for (int nt = 0; nt < 6; ++nt)
        acc[j][nt] = __builtin_amdgcn_mfma_f32_16x16x32_bf16(a5[j], b6[nt], acc[j][nt], 0, 0, 0);
  }
  // qk epilogue: Pt[b][n][o], o = wv*16 + 4*(lane>>4)+rr
  {
    float* Ptb = Pt + (size_t)b * 589824;
    float4 bv = *(const float4*)(ball + wv * 16 + ((lane >> 4) << 2));
#pragma unroll
    for (int nt = 0; nt < 6; ++nt) {
      int n = h * 96 + nt * 16 + arow;
      f32x4 a = acc[0][nt];
      float4 r = make_float4(a[0] + bv.x, a[1] + bv.y, a[2] + bv.z, a[3] + bv.w);
      *(float4*)&Ptb[(size_t)n * 64 + wv * 16 + ((lane >> 4) << 2)] = r;
    }
  }
  __syncthreads();
  // v epilogue: 4 rounds of 64 channels, all waves contribute (wave w -> rows 16w..16w+15)
  for (int r = 0; r < 4; ++r) {
    int j = r + 1;
    float4 bv = *(const float4*)(ball + 64 + r * 64 + wv * 16 + ((lane >> 4) << 2));
    float ba[4] = {bv.x, bv.y, bv.z, bv.w};
#pragma unroll
    for (int nt = 0; nt < 6; ++nt) {
      int col = nt * 16 + arow;
#pragma unroll
      for (int rr = 0; rr < 4; ++rr) {
        int lrow = wv * 16 + ((lane >> 4) << 2) + rr;
        sO[lrow * 104 + col] = f2bf(acc[j][nt][rr] + ba[rr]);
      }
    }
    __syncthreads();
    for (int idx = tid; idx < 768; idx += 256) {
      int cc = idx / 12, c4 = idx % 12;
      *(float4*)(vW + ((size_t)(b * 96 + h) * 256 + r * 64 + cc) * 96 + c4 * 8) =
          *(const float4*)&sO[cc * 104 + c4 * 8];
    }
    __syncthreads();
  }
}

// vH[b][w][c][g] = vW[b][g][c][w]
__global__ __launch_bounds__(256) void vtrans(const u16* __restrict__ vW, u16* __restrict__ vH) {
  __shared__ u16 t[96][98];
  const int c = blockIdx.x, b = blockIdx.y;
  for (int idx = threadIdx.x; idx < 4608; idx += 256) {
    int hh = idx / 48, w2 = idx % 48;
    *(unsigned int*)&t[hh][w2 * 2] =
        *(const unsigned int*)(vW + (size_t)(b * 96 + hh) * 24576 + c * 96 + w2 * 2);
  }
  __syncthreads();
  for (int idx = threadIdx.x; idx < 4608; idx += 256) {
    int ww = idx / 48, g2 = idx % 48;
    unsigned int lo = t[g2 * 2][ww];
    unsigned int hi = t[g2 * 2 + 1][ww];
    *(unsigned int*)(vH + (size_t)(b * 96 + ww) * 24576 + c * 96 + g2 * 2) = lo | (hi << 16);
  }
}

// ISH=0: block (b,h) over e_w; ISH=1: block (b,w) over e_h (diag-masked).
// qs/ks overlay vbuf (disjoint lifetimes) -> 46.6 KB LDS -> 3 blocks/CU.
template <int ISH>
__global__ __launch_bounds__(384, 3) void attn_pass(const float* __restrict__ Qpt, const float* __restrict__ Kpt,
                                                    const u16* __restrict__ Vp, float* __restrict__ mOut,
                                                    float* __restrict__ sOut, u16* __restrict__ tOut) {
  __shared__ __align__(16) char smem[46592];
  float* qs = (float*)smem;            // [32][100]
  float* ks = (float*)(smem + 12800);  // [32][100]
  u16* vbuf = (u16*)smem;              // [128][104] overlays qs/ks
  u16* probs = (u16*)(smem + 26624);   // [96][104]
  const int p = blockIdx.x, b = blockIdx.y;
  const int tid = threadIdx.x;
  const size_t pbase = (size_t)b * 589824 + (size_t)(ISH ? p : p * 96) * 64;
  const int rstride = ISH ? 6144 : 64;
  for (int idx = tid; idx < 1536; idx += 384) {
    int i = idx >> 4, c4 = idx & 15;
    const float* src = (c4 < 8 ? Qpt : Kpt) + pbase + (size_t)i * rstride + c4 * 4;
    float4 v = *(const float4*)src;
    float* dst = (c4 < 8) ? &qs[c4 * 4 * 100 + i] : &ks[(c4 - 8) * 4 * 100 + i];
    dst[0] = v.x; dst[100] = v.y; dst[200] = v.z; dst[300] = v.w;
  }
  __syncthreads();
  const int row_ = tid >> 2, j = tid & 3;
  float e[24];
#pragma unroll
  for (int t = 0; t < 24; ++t) e[t] = 0.f;
  for (int cq = 0; cq < 32; ++cq) {
    float qv = qs[cq * 100 + row_];
    const float4* k4 = (const float4*)&ks[cq * 100 + j * 24];
#pragma unroll
    for (int t4 = 0; t4 < 6; ++t4) {
      float4 kk = k4[t4];
      e[t4 * 4 + 0] += qv * kk.x; e[t4 * 4 + 1] += qv * kk.y;
      e[t4 * 4 + 2] += qv * kk.z; e[t4 * 4 + 3] += qv * kk.w;
    }
  }
  if (ISH) {
#pragma unroll
    for (int t = 0; t < 24; ++t)
      if (j * 24 + t == row_) e[t] = -1e30f;
  }
  float mx = -1e30f;
#pragma unroll
  for (int t = 0; t < 24; ++t) mx = fmaxf(mx, e[t]);
  mx = fmaxf(mx, __shfl_xor(mx, 1));
  mx = fmaxf(mx, __shfl_xor(mx, 2));
  float s = 0.f;
#pragma unroll
  for (int t = 0; t < 24; ++t) {
    float pv = __expf(e[t] - mx);
    e[t] = pv; s += pv;
  }
  s += __shfl_xor(s, 1);
  s += __shfl_xor(s, 2);
  if (j == 0) {
    size_t sidx = ISH ? ((size_t)(b * 96 + row_) * 96 + p) : ((size_t)(b * 96 + p) * 96 + row_);
    mOut[sidx] = mx; sOut[sidx] = s;
  }
  unsigned int* prow = (unsigned int*)&probs[row_ * 104 + j * 24];
#pragma unroll
  for (int p2 = 0; p2 < 12; ++p2) {
    unsigned int lo = f2bf(e[2 * p2]), hi = f2bf(e[2 * p2 + 1]);
    prow[p2] = lo | (hi << 16);
  }
  __syncthreads();
  const int lane = tid & 63, wv = tid >> 6;
  const int w0 = wv * 16;
  const int kc = (lane >> 4) * 8;
  bf16x8 af[3];
#pragma unroll
  for (int kt = 0; kt < 3; ++kt)
    af[kt] = *(const bf16x8*)&probs[(w0 + (lane & 15)) * 104 + kt * 32 + kc];
  const size_t vbase = (size_t)(b * 96 + p) * 24576;
  for (int half = 0; half < 2; ++half) {
    for (int idx = tid; idx < 1536; idx += 384) {
      int r = idx / 12, c4 = idx % 12;
      *(float4*)&vbuf[r * 104 + c4 * 8] = *(const float4*)(Vp + vbase + (size_t)(half * 128 + r) * 96 + c4 * 8);
    }
    __syncthreads();
    f32x4 acc[8];
#pragma unroll
    for (int nt = 0; nt < 8; ++nt) {
      f32x4 a = {0.f, 0.f, 0.f, 0.f};
#pragma unroll
      for (int kt = 0; kt < 3; ++kt) {
        bf16x8 bf = *(const bf16x8*)&vbuf[(nt * 16 + (lane & 15)) * 104 + kt * 32 + kc];
        a = __builtin_amdgcn_mfma_f32_16x16x32_bf16(af[kt], bf, a, 0, 0, 0);
      }
      acc[nt] = a;
    }
    __syncthreads();
#pragma unroll
    for (int nt = 0; nt < 8; ++nt) {
      int c2 = nt * 16 + (lane & 15);
      int wr = w0 + ((lane >> 4) << 2);
#pragma unroll
      for (int r = 0; r < 4; ++r) vbuf[c2 * 104 + wr + r] = f2bf(acc[nt][r]);
    }
    __syncthreads();
    for (int idx = tid; idx < 1536; idx += 384) {
      int r = idx / 12, c4 = idx % 12;
      *(float4*)(tOut + vbase + (size_t)(half * 128 + r) * 96 + c4 * 8) = *(const float4*)&vbuf[r * 104 + c4 * 8];
    }
    __syncthreads();
  }
}

// Exact concat-softmax rescale: m=max(mh,mw), s=sh*e^(mh-m)+sw*e^(mw-m); scl*=gamma/s.
__global__ __launch_bounds__(256) void scl_k(const float* __restrict__ mH, const float* __restrict__ sH,
                                             const float* __restrict__ mW, const float* __restrict__ sW,
                                             const float* __restrict__ gammaP, float* __restrict__ sclH,
                                             float* __restrict__ sclW) {
  int i = blockIdx.x * 256 + threadIdx.x;
  if (i >= Bn * 9216) return;
  float mh = mH[i], mw = mW[i];
  float m = fmaxf(mh, mw);
  float eh = __expf(mh - m), ew = __expf(mw - m);
  float s = sH[i] * eh + sW[i] * ew;
  float g = gammaP[0] / s;
  sclH[i] = g * eh;
  sclW[i] = g * ew;
}

// out[b][c][h][w] = x + tmpH[b][w][c][h]*sclH[h][w] + tmpW[b][h][c][w]*sclW[h][w]
__global__ __launch_bounds__(256) void tkomb(const u16* __restrict__ tmpH, const u16* __restrict__ tmpW,
                                             const float* __restrict__ x, const float* __restrict__ sclH,
                                             const float* __restrict__ sclW, float* __restrict__ out) {
  __shared__ u16 t[96][108];
  const int c = blockIdx.x, b = blockIdx.y;
  const int tid = threadIdx.x;
  for (int idx = tid; idx < 2304; idx += 256) {
    int w_ = idx / 24, h4 = idx % 24;
    *(ushort4*)&t[w_][h4 * 4] =
        *(const ushort4*)(tmpH + ((size_t)(b * 96 + w_) * 256 + c) * 96 + h4 * 4);
  }
  __syncthreads();
  for (int idx = tid; idx < 2304; idx += 256) {
    int h_ = idx / 24, w4 = idx % 24;
    size_t go = ((size_t)(b * 256 + c) * 96 + h_) * 96 + w4 * 4;
    float4 xv = *(const float4*)(x + go);
    ushort4 wvv = *(const ushort4*)(tmpW + ((size_t)(b * 96 + h_) * 256 + c) * 96 + w4 * 4);
    float4 sh4 = *(const float4*)(sclH + (size_t)(b * 96 + h_) * 96 + w4 * 4);
    float4 sw4 = *(const float4*)(sclW + (size_t)(b * 96 + h_) * 96 + w4 * 4);
    float4 ov;
    ov.x = xv.x + bf2f(t[w4 * 4 + 0][h_]) * sh4.x + bf2f(wvv.x) * sw4.x;
    ov.y = xv.y + bf2f(t[w4 * 4 + 1][h_]) * sh4.y + bf2f(wvv.y) * sw4.y;
    ov.z = xv.z + bf2f(t[w4 * 4 + 2][h_]) * sh4.z + bf2f(wvv.z) * sw4.z;
    ov.w = xv.w + bf2f(t[w4 * 4 + 3][h_]) * sh4.w + bf2f(wvv.w) * sw4.w;
    *(float4*)(out + go) = ov;
  }
}

extern "C" void kernel_launch(void* const* d_in, const int* in_sizes, int n_in,
                              void* d_out, int out_size, void* d_ws, size_t ws_size,
                              hipStream_t stream) {
  const float* x0 = (const float*)d_in[0];
  const float* x1 = (const float*)d_in[1];
  const float* wq0 = (const float*)d_in[2];
  const float* bq0 = (const float*)d_in[3];
  const float* wk0 = (const float*)d_in[4];
  const float* bk0 = (const float*)d_in[5];
  const float* wv0 = (const float*)d_in[6];
  const float* bv0 = (const float*)d_in[7];
  const float* wq1 = (const float*)d_in[8];
  const float* bq1 = (const float*)d_in[9];
  const float* wk1 = (const float*)d_in[10];
  const float* bk1 = (const float*)d_in[11];
  const float* wv1 = (const float*)d_in[12];
  const float* bv1 = (const float*)d_in[13];
  const float* gamma = (const float*)d_in[14];
  float* out = (float*)d_out;

  char* ws = (char*)d_ws;
  size_t off = 0;
  auto alloc = [&](size_t bytes) -> void* {
    void* ptr = ws + off;
    off += (bytes + 255) & ~(size_t)255;
    return ptr;
  };
  const size_t SZ_P = (size_t)Bn * NHW * 64 * 4;   // 18.9 MB
  const size_t SZ_V = (size_t)Bn * NHW * Cn * 2;   // 37.7 MB
  const size_t SZ_S = (size_t)Bn * 9216 * 4;       // 294 KB
  float* Pt0 = (float*)alloc(SZ_P);
  float* Pt1 = (float*)alloc(SZ_P);
  u16* vW0 = (u16*)alloc(SZ_V);
  u16* vW1 = (u16*)alloc(SZ_V);
  u16* vH = (u16*)alloc(SZ_V);
  u16* tmpW = (u16*)alloc(SZ_V);
  u16* tmpH = (u16*)alloc(SZ_V);
  u16* Wall0 = (u16*)alloc(320 * 256 * 2);
  u16* Wall1 = (u16*)alloc(320 * 256 * 2);
  float* ball0 = (float*)alloc(320 * 4);
  float* ball1 = (float*)alloc(320 * 4);
  float* mH = (float*)alloc(SZ_S);
  float* sH = (float*)alloc(SZ_S);
  float* mW = (float*)alloc(SZ_S);
  float* sW = (float*)alloc(SZ_S);
  float* sclH = (float*)alloc(SZ_S);
  float* sclW = (float*)alloc(SZ_S);
  (void)ws_size; (void)in_sizes; (void)n_in; (void)out_size;

  pack_all<<<320, 256, 0, stream>>>(wq0, bq0, wk0, bk0, wv0, bv0, Wall0, ball0);
  pack_all<<<320, 256, 0, stream>>>(wq1, bq1, wk1, bk1, wv1, bv1, Wall1, ball1);

  dim3 gp(96, Bn), gc(256, Bn);
  proj_all<<<gp, 256, 0, stream>>>(x0, Wall0, ball0, Pt0, vW0);
  proj_all<<<gp, 256, 0, stream>>>(x1, Wall1, ball1, Pt1, vW1);

  // pair 0: cat0 = gamma * attend(q1, k0, v0) + x0
  vtrans<<<gc, 256, 0, stream>>>(vW0, vH);
  attn_pass<0><<<gp, 384, 0, stream>>>(Pt1, Pt0, vW0, mW, sW, tmpW);
  attn_pass<1><<<gp, 384, 0, stream>>>(Pt1, Pt0, vH, mH, sH, tmpH);
  scl_k<<<288, 256, 0, stream>>>(mH, sH, mW, sW, gamma, sclH, sclW);
  tkomb<<<gc, 256, 0, stream>>>(tmpH, tmpW, x0, sclH, sclW, out);

  // pair 1: cat1 = gamma * attend(q0, k1, v1) + x1
  vtrans<<<gc, 256, 0, stream>>>(vW1, vH);
  attn_pass<0><<<gp, 384, 0, stream>>>(Pt0, Pt1, vW1, mW, sW, tmpW);
  attn_pass<1><<<gp, 384, 0, stream>>>(Pt0, Pt1, vH, mH, sH, tmpH);
  scl_k<<<288, 256, 0, stream>>>(mH, sH, mW, sW, gamma, sclH, sclW);
  tkomb<<<gc, 256, 0, stream>>>(tmpH, tmpW, x1, sclH, sclW, out + (size_t)Bn * Cn * NHW);
}

// Round 5
// 401.670 us; speedup vs baseline: 7.8951x; 1.0032x over previous
//
#include <hip/hip_runtime.h>
#include <hip/hip_bf16.h>

// CrissCross attention, B=8 C=256 H=W=96 CQ=32. Flash-style split softmax,
// all low-precision operands in fp16 (11-bit mantissa vs bf16's 8 -> 8x less
// quantization error; f16 MFMA runs at the bf16 rate on gfx950):
//  pack_all : [wq|wk|wv] -> f16 Wall[320][256] + fp32 ball[320] per input
//  proj_all : one f16-MFMA pass, block (h,b): x row-tile staged once ->
//             q,k fp32 Pt[b][n][64] (n-major) + v f16 vW[b][h][c][w]
//  vtrans   : vW -> vH[b][w][c][g]
//  attn<0>  : per (b,h): e_w once, local stats (mW,sW), out_w' -> tmpW[b][h][c][w]
//  attn<1>  : per (b,w): e_h (diag mask), stats (mH,sH), out_h' -> tmpH[b][w][c][h]
//  scl      : exact concat-softmax rescale sclH/sclW[b][h][w] (gamma folded)
//  tkomb    : out = x + tmpH^T*sclH + tmpW*sclW (transpose fused)

#define Bn 8
#define Cn 256
#define NHW 9216

typedef unsigned short u16;
typedef __attribute__((ext_vector_type(8))) _Float16 f16x8;
typedef __attribute__((ext_vector_type(4))) float f32x4;

__device__ __forceinline__ float h2f(u16 v) {
  _Float16 h;
  __builtin_memcpy(&h, &v, 2);
  return (float)h;
}
__device__ __forceinline__ u16 f2h(float f) {
  _Float16 h = (_Float16)f;
  u16 v;
  __builtin_memcpy(&v, &h, 2);
  return v;
}

__global__ __launch_bounds__(256) void pack_all(const float* __restrict__ wq, const float* __restrict__ bq,
                                                const float* __restrict__ wk, const float* __restrict__ bk,
                                                const float* __restrict__ wv, const float* __restrict__ bv,
                                                u16* __restrict__ Wall, float* __restrict__ ball) {
  int i = blockIdx.x * 256 + threadIdx.x;
  if (i < 320 * 256) {
    int o = i >> 8, c = i & 255;
    float v = (o < 32) ? wq[o * 256 + c] : (o < 64) ? wk[(o - 32) * 256 + c] : wv[(o - 64) * 256 + c];
    Wall[i] = f2h(v);
  }
  if (i < 320) ball[i] = (i < 32) ? bq[i] : (i < 64) ? bk[i - 32] : bv[i - 64];
}

// Fused projection: block (h, b). M=320 outputs, N=96 (one h-row), K=256, f16 MFMA.
// Wave w owns m-tiles {w, w+4, w+8, w+12, w+16}: first = qk, rest = v.
__global__ __launch_bounds__(256, 2) void proj_all(const float* __restrict__ X, const u16* __restrict__ Wall,
                                                   const float* __restrict__ ball, float* __restrict__ Pt,
                                                   u16* __restrict__ vW) {
  __shared__ u16 xs[96][264];  // f16 x-tile [n][cin], 50688 B
  u16* sO = &xs[0][0];         // overlay [128][104] (26624 B) for v epilogue
  const int h = blockIdx.x, b = blockIdx.y;
  const int tid = threadIdx.x;
  const float* Xb = X + (size_t)b * Cn * NHW + h * 96;
  for (int idx = tid; idx < 6144; idx += 256) {
    int cin = idx / 24, n4 = idx % 24;
    float4 v = *(const float4*)(Xb + (size_t)cin * NHW + n4 * 4);
    xs[n4 * 4 + 0][cin] = f2h(v.x);
    xs[n4 * 4 + 1][cin] = f2h(v.y);
    xs[n4 * 4 + 2][cin] = f2h(v.z);
    xs[n4 * 4 + 3][cin] = f2h(v.w);
  }
  __syncthreads();
  const int lane = tid & 63, wv = tid >> 6;
  const int arow = lane & 15;
  const int kc = (lane >> 4) * 8;
  f32x4 acc[5][6] = {};
#pragma unroll
  for (int kk = 0; kk < 8; ++kk) {
    f16x8 a5[5], b6[6];
#pragma unroll
    for (int j = 0; j < 5; ++j)
      a5[j] = *(const f16x8*)(Wall + (size_t)((wv + 4 * j) * 16 + arow) * 256 + kk * 32 + kc);
#pragma unroll
    for (int nt = 0; nt < 6; ++nt)
      b6[nt] = *(const f16x8*)&xs[nt * 16 + arow][kk * 32 + kc];
#pragma unroll
    for (int j = 0; j < 5; ++j)
#pragma unroll
      for (int nt = 0; nt < 6; ++nt)
        acc[j][nt] = __builtin_amdgcn_mfma_f32_16x16x32_f16(a5[j], b6[nt], acc[j][nt], 0, 0, 0);
  }
  // qk epilogue: Pt[b][n][o], o = wv*16 + 4*(lane>>4)+rr
  {
    float* Ptb = Pt + (size_t)b * 589824;
    float4 bv = *(const float4*)(ball + wv * 16 + ((lane >> 4) << 2));
#pragma unroll
    for (int nt = 0; nt < 6; ++nt) {
      int n = h * 96 + nt * 16 + arow;
      f32x4 a = acc[0][nt];
      float4 r = make_float4(a[0] + bv.x, a[1] + bv.y, a[2] + bv.z, a[3] + bv.w);
      *(float4*)&Ptb[(size_t)n * 64 + wv * 16 + ((lane >> 4) << 2)] = r;
    }
  }
  __syncthreads();
  // v epilogue: 2 rounds of 128 channels (j-tiles 2r+1, 2r+2)
  for (int r = 0; r < 2; ++r) {
#pragma unroll
    for (int jj = 0; jj < 2; ++jj) {
      int j = 2 * r + 1 + jj;
      float4 bv = *(const float4*)(ball + 64 + (j - 1) * 64 + wv * 16 + ((lane >> 4) << 2));
      float ba[4] = {bv.x, bv.y, bv.z, bv.w};
#pragma unroll
      for (int nt = 0; nt < 6; ++nt) {
        int col = nt * 16 + arow;
#pragma unroll
        for (int rr = 0; rr < 4; ++rr) {
          int lrow = jj * 64 + wv * 16 + ((lane >> 4) << 2) + rr;
          sO[lrow * 104 + col] = f2h(acc[j][nt][rr] + ba[rr]);
        }
      }
    }
    __syncthreads();
    for (int idx = tid; idx < 1536; idx += 256) {
      int cc = idx / 12, c4 = idx % 12;
      *(float4*)(vW + ((size_t)(b * 96 + h) * 256 + r * 128 + cc) * 96 + c4 * 8) =
          *(const float4*)&sO[cc * 104 + c4 * 8];
    }
    __syncthreads();
  }
}

// vH[b][w][c][g] = vW[b][g][c][w]
__global__ __launch_bounds__(256) void vtrans(const u16* __restrict__ vW, u16* __restrict__ vH) {
  __shared__ u16 t[96][98];
  const int c = blockIdx.x, b = blockIdx.y;
  for (int idx = threadIdx.x; idx < 4608; idx += 256) {
    int hh = idx / 48, w2 = idx % 48;
    *(unsigned int*)&t[hh][w2 * 2] =
        *(const unsigned int*)(vW + (size_t)(b * 96 + hh) * 24576 + c * 96 + w2 * 2);
  }
  __syncthreads();
  for (int idx = threadIdx.x; idx < 4608; idx += 256) {
    int ww = idx / 48, g2 = idx % 48;
    unsigned int lo = t[g2 * 2][ww];
    unsigned int hi = t[g2 * 2 + 1][ww];
    *(unsigned int*)(vH + (size_t)(b * 96 + ww) * 24576 + c * 96 + g2 * 2) = lo | (hi << 16);
  }
}

// ISH=0: block (b,h) over e_w; ISH=1: block (b,w) over e_h (diag-masked).
// qs/ks overlay vbuf (disjoint lifetimes) -> 46.6 KB LDS -> 3 blocks/CU.
template <int ISH>
__global__ __launch_bounds__(384, 3) void attn_pass(const float* __restrict__ Qpt, const float* __restrict__ Kpt,
                                                    const u16* __restrict__ Vp, float* __restrict__ mOut,
                                                    float* __restrict__ sOut, u16* __restrict__ tOut) {
  __shared__ __align__(16) char smem[46592];
  float* qs = (float*)smem;            // [32][100]
  float* ks = (float*)(smem + 12800);  // [32][100]
  u16* vbuf = (u16*)smem;              // [128][104] overlays qs/ks
  u16* probs = (u16*)(smem + 26624);   // [96][104]
  const int p = blockIdx.x, b = blockIdx.y;
  const int tid = threadIdx.x;
  const size_t pbase = (size_t)b * 589824 + (size_t)(ISH ? p : p * 96) * 64;
  const int rstride = ISH ? 6144 : 64;
  for (int idx = tid; idx < 1536; idx += 384) {
    int i = idx >> 4, c4 = idx & 15;
    const float* src = (c4 < 8 ? Qpt : Kpt) + pbase + (size_t)i * rstride + c4 * 4;
    float4 v = *(const float4*)src;
    float* dst = (c4 < 8) ? &qs[c4 * 4 * 100 + i] : &ks[(c4 - 8) * 4 * 100 + i];
    dst[0] = v.x; dst[100] = v.y; dst[200] = v.z; dst[300] = v.w;
  }
  __syncthreads();
  const int row_ = tid >> 2, j = tid & 3;
  float e[24];
#pragma unroll
  for (int t = 0; t < 24; ++t) e[t] = 0.f;
  for (int cq = 0; cq < 32; ++cq) {
    float qv = qs[cq * 100 + row_];
    const float4* k4 = (const float4*)&ks[cq * 100 + j * 24];
#pragma unroll
    for (int t4 = 0; t4 < 6; ++t4) {
      float4 kk = k4[t4];
      e[t4 * 4 + 0] += qv * kk.x; e[t4 * 4 + 1] += qv * kk.y;
      e[t4 * 4 + 2] += qv * kk.z; e[t4 * 4 + 3] += qv * kk.w;
    }
  }
  if (ISH) {
#pragma unroll
    for (int t = 0; t < 24; ++t)
      if (j * 24 + t == row_) e[t] = -1e30f;
  }
  float mx = -1e30f;
#pragma unroll
  for (int t = 0; t < 24; ++t) mx = fmaxf(mx, e[t]);
  mx = fmaxf(mx, __shfl_xor(mx, 1));
  mx = fmaxf(mx, __shfl_xor(mx, 2));
  float s = 0.f;
#pragma unroll
  for (int t = 0; t < 24; ++t) {
    float pv = __expf(e[t] - mx);
    e[t] = pv; s += pv;
  }
  s += __shfl_xor(s, 1);
  s += __shfl_xor(s, 2);
  if (j == 0) {
    size_t sidx = ISH ? ((size_t)(b * 96 + row_) * 96 + p) : ((size_t)(b * 96 + p) * 96 + row_);
    mOut[sidx] = mx; sOut[sidx] = s;
  }
  unsigned int* prow = (unsigned int*)&probs[row_ * 104 + j * 24];
#pragma unroll
  for (int p2 = 0; p2 < 12; ++p2) {
    unsigned int lo = f2h(e[2 * p2]), hi = f2h(e[2 * p2 + 1]);
    prow[p2] = lo | (hi << 16);
  }
  __syncthreads();
  const int lane = tid & 63, wv = tid >> 6;
  const int w0 = wv * 16;
  const int kc = (lane >> 4) * 8;
  f16x8 af[3];
#pragma unroll
  for (int kt = 0; kt < 3; ++kt)
    af[kt] = *(const f16x8*)&probs[(w0 + (lane & 15)) * 104 + kt * 32 + kc];
  const size_t vbase = (size_t)(b * 96 + p) * 24576;
  for (int half = 0; half < 2; ++half) {
    for (int idx = tid; idx < 1536; idx += 384) {
      int r = idx / 12, c4 = idx % 12;
      *(float4*)&vbuf[r * 104 + c4 * 8] = *(const float4*)(Vp + vbase + (size_t)(half * 128 + r) * 96 + c4 * 8);
    }
    __syncthreads();
    f32x4 acc[8];
#pragma unroll
    for (int nt = 0; nt < 8; ++nt) {
      f32x4 a = {0.f, 0.f, 0.f, 0.f};
#pragma unroll
      for (int kt = 0; kt < 3; ++kt) {
        f16x8 bf = *(const f16x8*)&vbuf[(nt * 16 + (lane & 15)) * 104 + kt * 32 + kc];
        a = __builtin_amdgcn_mfma_f32_16x16x32_f16(af[kt], bf, a, 0, 0, 0);
      }
      acc[nt] = a;
    }
    __syncthreads();
#pragma unroll
    for (int nt = 0; nt < 8; ++nt) {
      int c2 = nt * 16 + (lane & 15);
      int wr = w0 + ((lane >> 4) << 2);
#pragma unroll
      for (int r = 0; r < 4; ++r) vbuf[c2 * 104 + wr + r] = f2h(acc[nt][r]);
    }
    __syncthreads();
    for (int idx = tid; idx < 1536; idx += 384) {
      int r = idx / 12, c4 = idx % 12;
      *(float4*)(tOut + vbase + (size_t)(half * 128 + r) * 96 + c4 * 8) = *(const float4*)&vbuf[r * 104 + c4 * 8];
    }
    __syncthreads();
  }
}

// Exact concat-softmax rescale: m=max(mh,mw), s=sh*e^(mh-m)+sw*e^(mw-m); scl*=gamma/s.
__global__ __launch_bounds__(256) void scl_k(const float* __restrict__ mH, const float* __restrict__ sH,
                                             const float* __restrict__ mW, const float* __restrict__ sW,
                                             const float* __restrict__ gammaP, float* __restrict__ sclH,
                                             float* __restrict__ sclW) {
  int i = blockIdx.x * 256 + threadIdx.x;
  if (i >= Bn * 9216) return;
  float mh = mH[i], mw = mW[i];
  float m = fmaxf(mh, mw);
  float eh = __expf(mh - m), ew = __expf(mw - m);
  float s = sH[i] * eh + sW[i] * ew;
  float g = gammaP[0] / s;
  sclH[i] = g * eh;
  sclW[i] = g * ew;
}

// out[b][c][h][w] = x + tmpH[b][w][c][h]*sclH[h][w] + tmpW[b][h][c][w]*sclW[h][w]
__global__ __launch_bounds__(256) void tkomb(const u16* __restrict__ tmpH, const u16* __restrict__ tmpW,
                                             const float* __restrict__ x, const float* __restrict__ sclH,
                                             const float* __restrict__ sclW, float* __restrict__ out) {
  __shared__ u16 t[96][108];
  const int c = blockIdx.x, b = blockIdx.y;
  const int tid = threadIdx.x;
  for (int idx = tid; idx < 2304; idx += 256) {
    int w_ = idx / 24, h4 = idx % 24;
    *(ushort4*)&t[w_][h4 * 4] =
        *(const ushort4*)(tmpH + ((size_t)(b * 96 + w_) * 256 + c) * 96 + h4 * 4);
  }
  __syncthreads();
  for (int idx = tid; idx < 2304; idx += 256) {
    int h_ = idx / 24, w4 = idx % 24;
    size_t go = ((size_t)(b * 256 + c) * 96 + h_) * 96 + w4 * 4;
    float4 xv = *(const float4*)(x + go);
    ushort4 wvv = *(const ushort4*)(tmpW + ((size_t)(b * 96 + h_) * 256 + c) * 96 + w4 * 4);
    float4 sh4 = *(const float4*)(sclH + (size_t)(b * 96 + h_) * 96 + w4 * 4);
    float4 sw4 = *(const float4*)(sclW + (size_t)(b * 96 + h_) * 96 + w4 * 4);
    float4 ov;
    ov.x = xv.x + h2f(t[w4 * 4 + 0][h_]) * sh4.x + h2f(wvv.x) * sw4.x;
    ov.y = xv.y + h2f(t[w4 * 4 + 1][h_]) * sh4.y + h2f(wvv.y) * sw4.y;
    ov.z = xv.z + h2f(t[w4 * 4 + 2][h_]) * sh4.z + h2f(wvv.z) * sw4.z;
    ov.w = xv.w + h2f(t[w4 * 4 + 3][h_]) * sh4.w + h2f(wvv.w) * sw4.w;
    *(float4*)(out + go) = ov;
  }
}

extern "C" void kernel_launch(void* const* d_in, const int* in_sizes, int n_in,
                              void* d_out, int out_size, void* d_ws, size_t ws_size,
                              hipStream_t stream) {
  const float* x0 = (const float*)d_in[0];
  const float* x1 = (const float*)d_in[1];
  const float* wq0 = (const float*)d_in[2];
  const float* bq0 = (const float*)d_in[3];
  const float* wk0 = (const float*)d_in[4];
  const float* bk0 = (const float*)d_in[5];
  const float* wv0 = (const float*)d_in[6];
  const float* bv0 = (const float*)d_in[7];
  const float* wq1 = (const float*)d_in[8];
  const float* bq1 = (const float*)d_in[9];
  const float* wk1 = (const float*)d_in[10];
  const float* bk1 = (const float*)d_in[11];
  const float* wv1 = (const float*)d_in[12];
  const float* bv1 = (const float*)d_in[13];
  const float* gamma = (const float*)d_in[14];
  float* out = (float*)d_out;

  char* ws = (char*)d_ws;
  size_t off = 0;
  auto alloc = [&](size_t bytes) -> void* {
    void* ptr = ws + off;
    off += (bytes + 255) & ~(size_t)255;
    return ptr;
  };
  const size_t SZ_P = (size_t)Bn * NHW * 64 * 4;   // 18.9 MB
  const size_t SZ_V = (size_t)Bn * NHW * Cn * 2;   // 37.7 MB
  const size_t SZ_S = (size_t)Bn * 9216 * 4;       // 294 KB
  float* Pt0 = (float*)alloc(SZ_P);
  float* Pt1 = (float*)alloc(SZ_P);
  u16* vW0 = (u16*)alloc(SZ_V);
  u16* vW1 = (u16*)alloc(SZ_V);
  u16* vH = (u16*)alloc(SZ_V);
  u16* tmpW = (u16*)alloc(SZ_V);
  u16* tmpH = (u16*)alloc(SZ_V);
  u16* Wall0 = (u16*)alloc(320 * 256 * 2);
  u16* Wall1 = (u16*)alloc(320 * 256 * 2);
  float* ball0 = (float*)alloc(320 * 4);
  float* ball1 = (float*)alloc(320 * 4);
  float* mH = (float*)alloc(SZ_S);
  float* sH = (float*)alloc(SZ_S);
  float* mW = (float*)alloc(SZ_S);
  float* sW = (float*)alloc(SZ_S);
  float* sclH = (float*)alloc(SZ_S);
  float* sclW = (float*)alloc(SZ_S);
  (void)ws_size; (void)in_sizes; (void)n_in; (void)out_size;

  pack_all<<<320, 256, 0, stream>>>(wq0, bq0, wk0, bk0, wv0, bv0, Wall0, ball0);
  pack_all<<<320, 256, 0, stream>>>(wq1, bq1, wk1, bk1, wv1, bv1, Wall1, ball1);

  dim3 gp(96, Bn), gc(256, Bn);
  proj_all<<<gp, 256, 0, stream>>>(x0, Wall0, ball0, Pt0, vW0);
  proj_all<<<gp, 256, 0, stream>>>(x1, Wall1, ball1, Pt1, vW1);

  // pair 0: cat0 = gamma * attend(q1, k0, v0) + x0
  vtrans<<<gc, 256, 0, stream>>>(vW0, vH);
  attn_pass<0><<<gp, 384, 0, stream>>>(Pt1, Pt0, vW0, mW, sW, tmpW);
  attn_pass<1><<<gp, 384, 0, stream>>>(Pt1, Pt0, vH, mH, sH, tmpH);
  scl_k<<<288, 256, 0, stream>>>(mH, sH, mW, sW, gamma, sclH, sclW);
  tkomb<<<gc, 256, 0, stream>>>(tmpH, tmpW, x0, sclH, sclW, out);

  // pair 1: cat1 = gamma * attend(q0, k1, v1) + x1
  vtrans<<<gc, 256, 0, stream>>>(vW1, vH);
  attn_pass<0><<<gp, 384, 0, stream>>>(Pt0, Pt1, vW1, mW, sW, tmpW);
  attn_pass<1><<<gp, 384, 0, stream>>>(Pt0, Pt1, vH, mH, sH, tmpH);
  scl_k<<<288, 256, 0, stream>>>(mH, sH, mW, sW, gamma, sclH, sclW);
  tkomb<<<gc, 256, 0, stream>>>(tmpH, tmpW, x1, sclH, sclW, out + (size_t)Bn * Cn * NHW);
}

// Round 6
// 342.150 us; speedup vs baseline: 9.2685x; 1.1740x over previous
//
#include <hip/hip_runtime.h>
#include <hip/hip_bf16.h>

// CrissCross attention, B=8 C=256 H=W=96 CQ=32. Flash-style split softmax, fp16
// operands everywhere (f16 MFMA = bf16 rate on gfx950, 8x less quant error):
//  pack_all : [wq|wk|wv] -> f16 Wall[320][256] + fp32 ball[320] per input
//  proj_all : one f16-MFMA pass, block (h,b): x row-tile staged once ->
//             q,k f16 Pt[b][n][64] (n-major) + v f16 vW[b][h][c][w]
//  vtrans   : vW* -> vH*[b][w][c][g], both pairs in one launch (z)
//  attn     : z=0 (b,h) e_w pass / z=1 (b,w) e_h pass (diag mask); MFMA QK^T,
//             in-register wave softmax, local stats, MFMA PV -> tmpW/tmpH
//  scl      : exact concat-softmax rescale sclH/sclW[b][h][w] (gamma folded)
//  tkomb    : out = x + tmpH^T*sclH + tmpW*sclW (transpose fused)

#define Bn 8
#define Cn 256
#define NHW 9216

typedef unsigned short u16;
typedef __attribute__((ext_vector_type(8))) _Float16 f16x8;
typedef __attribute__((ext_vector_type(4))) float f32x4;

__device__ __forceinline__ float h2f(u16 v) {
  _Float16 h;
  __builtin_memcpy(&h, &v, 2);
  return (float)h;
}
__device__ __forceinline__ u16 f2h(float f) {
  _Float16 h = (_Float16)f;
  u16 v;
  __builtin_memcpy(&v, &h, 2);
  return v;
}

__global__ __launch_bounds__(256) void pack_all(const float* __restrict__ wq, const float* __restrict__ bq,
                                                const float* __restrict__ wk, const float* __restrict__ bk,
                                                const float* __restrict__ wv, const float* __restrict__ bv,
                                                u16* __restrict__ Wall, float* __restrict__ ball) {
  int i = blockIdx.x * 256 + threadIdx.x;
  if (i < 320 * 256) {
    int o = i >> 8, c = i & 255;
    float v = (o < 32) ? wq[o * 256 + c] : (o < 64) ? wk[(o - 32) * 256 + c] : wv[(o - 64) * 256 + c];
    Wall[i] = f2h(v);
  }
  if (i < 320) ball[i] = (i < 32) ? bq[i] : (i < 64) ? bk[i - 32] : bv[i - 64];
}

// Fused projection: block (h, b). M=320 outputs, N=96 (one h-row), K=256, f16 MFMA.
// Wave w owns m-tiles {w, w+4, w+8, w+12, w+16}: first = qk, rest = v.
__global__ __launch_bounds__(256, 2) void proj_all(const float* __restrict__ X, const u16* __restrict__ Wall,
                                                   const float* __restrict__ ball, u16* __restrict__ Pt,
                                                   u16* __restrict__ vW) {
  __shared__ u16 xs[96][264];  // f16 x-tile [n][cin], 50688 B
  u16* sO = &xs[0][0];         // overlay [128][104] (26624 B) for v epilogue
  const int h = blockIdx.x, b = blockIdx.y;
  const int tid = threadIdx.x;
  const float* Xb = X + (size_t)b * Cn * NHW + h * 96;
  for (int idx = tid; idx < 6144; idx += 256) {
    int cin = idx / 24, n4 = idx % 24;
    float4 v = *(const float4*)(Xb + (size_t)cin * NHW + n4 * 4);
    xs[n4 * 4 + 0][cin] = f2h(v.x);
    xs[n4 * 4 + 1][cin] = f2h(v.y);
    xs[n4 * 4 + 2][cin] = f2h(v.z);
    xs[n4 * 4 + 3][cin] = f2h(v.w);
  }
  __syncthreads();
  const int lane = tid & 63, wv = tid >> 6;
  const int arow = lane & 15;
  const int g = lane >> 4;
  const int kc = g * 8;
  f32x4 acc[5][6] = {};
#pragma unroll
  for (int kk = 0; kk < 8; ++kk) {
    f16x8 a5[5], b6[6];
#pragma unroll
    for (int j = 0; j < 5; ++j)
      a5[j] = *(const f16x8*)(Wall + (size_t)((wv + 4 * j) * 16 + arow) * 256 + kk * 32 + kc);
#pragma unroll
    for (int nt = 0; nt < 6; ++nt)
      b6[nt] = *(const f16x8*)&xs[nt * 16 + arow][kk * 32 + kc];
#pragma unroll
    for (int j = 0; j < 5; ++j)
#pragma unroll
      for (int nt = 0; nt < 6; ++nt)
        acc[j][nt] = __builtin_amdgcn_mfma_f32_16x16x32_f16(a5[j], b6[nt], acc[j][nt], 0, 0, 0);
  }
  // qk epilogue: f16 Pt[b][n][o], o = wv*16 + 4g + rr
  {
    u16* Ptb = Pt + (size_t)b * ((size_t)NHW * 64);
    float4 bv = *(const float4*)(ball + wv * 16 + (g << 2));
#pragma unroll
    for (int nt = 0; nt < 6; ++nt) {
      int n = h * 96 + nt * 16 + arow;
      f32x4 a = acc[0][nt];
      ushort4 r;
      r.x = f2h(a[0] + bv.x); r.y = f2h(a[1] + bv.y);
      r.z = f2h(a[2] + bv.z); r.w = f2h(a[3] + bv.w);
      *(ushort4*)&Ptb[(size_t)n * 64 + wv * 16 + (g << 2)] = r;
    }
  }
  __syncthreads();
  // v epilogue: 2 rounds of 128 channels (j-tiles 2r+1, 2r+2)
  for (int r = 0; r < 2; ++r) {
#pragma unroll
    for (int jj = 0; jj < 2; ++jj) {
      int j = 2 * r + 1 + jj;
      float4 bv = *(const float4*)(ball + 64 + (j - 1) * 64 + wv * 16 + (g << 2));
      float ba[4] = {bv.x, bv.y, bv.z, bv.w};
#pragma unroll
      for (int nt = 0; nt < 6; ++nt) {
        int col = nt * 16 + arow;
#pragma unroll
        for (int rr = 0; rr < 4; ++rr) {
          int lrow = jj * 64 + wv * 16 + (g << 2) + rr;
          sO[lrow * 104 + col] = f2h(acc[j][nt][rr] + ba[rr]);
        }
      }
    }
    __syncthreads();
    for (int idx = tid; idx < 1536; idx += 256) {
      int cc = idx / 12, c4 = idx % 12;
      *(float4*)(vW + ((size_t)(b * 96 + h) * 256 + r * 128 + cc) * 96 + c4 * 8) =
          *(const float4*)&sO[cc * 104 + c4 * 8];
    }
    __syncthreads();
  }
}

// vH[b][w][c][g] = vW[b][g][c][w], both pairs (z selects)
__global__ __launch_bounds__(256) void vtrans(const u16* __restrict__ vW0, const u16* __restrict__ vW1,
                                              u16* __restrict__ vH0, u16* __restrict__ vH1) {
  __shared__ u16 t[96][98];
  const int c = blockIdx.x, b = blockIdx.y;
  const u16* vWp = blockIdx.z ? vW1 : vW0;
  u16* vHp = blockIdx.z ? vH1 : vH0;
  for (int idx = threadIdx.x; idx < 4608; idx += 256) {
    int hh = idx / 48, w2 = idx % 48;
    *(unsigned int*)&t[hh][w2 * 2] =
        *(const unsigned int*)(vWp + (size_t)(b * 96 + hh) * 24576 + c * 96 + w2 * 2);
  }
  __syncthreads();
  for (int idx = threadIdx.x; idx < 4608; idx += 256) {
    int ww = idx / 48, g2 = idx % 48;
    unsigned int lo = t[g2 * 2][ww];
    unsigned int hi = t[g2 * 2 + 1][ww];
    *(unsigned int*)(vHp + (size_t)(b * 96 + ww) * 24576 + c * 96 + g2 * 2) = lo | (hi << 16);
  }
}

// Merged attn: z=0 (b,h-row) e_w pass; z=1 (b,w-col) e_h pass (diag-masked).
// MFMA QK^T (wave wv owns M-rows [16wv,16wv+16)), in-register softmax over cols,
// unnormalized probs -> LDS f16 -> MFMA PV -> tmp.
__global__ __launch_bounds__(384, 3) void attn_fused(const u16* __restrict__ Qpt, const u16* __restrict__ Kpt,
                                                     const u16* __restrict__ vWp, const u16* __restrict__ vHp,
                                                     float* __restrict__ mW, float* __restrict__ sW,
                                                     float* __restrict__ mH, float* __restrict__ sH,
                                                     u16* __restrict__ tmpW, u16* __restrict__ tmpH) {
  __shared__ __align__(16) char smem[46592];
  u16* vbuf = (u16*)smem;             // [128][104]
  u16* qs = (u16*)smem;               // [96][40] overlays vbuf
  u16* ks = (u16*)(smem + 7680);      // [96][40]
  u16* probs = (u16*)(smem + 26624);  // [96][104]
  const int p = blockIdx.x, b = blockIdx.y, z = blockIdx.z;
  const int tid = threadIdx.x;
  const size_t nbase = (size_t)b * ((size_t)NHW * 64);
  const size_t rowoff = z ? (size_t)p * 64 : (size_t)p * 6144;
  const int rstride = z ? 6144 : 64;
  // load q (ch 0..31) and k (ch 32..63) rows as f16
  for (int idx = tid; idx < 768; idx += 384) {
    int i = idx >> 3, c8 = idx & 7;
    const u16* src = (c8 < 4)
        ? Qpt + nbase + rowoff + (size_t)i * rstride + c8 * 8
        : Kpt + nbase + rowoff + (size_t)i * rstride + 32 + (c8 - 4) * 8;
    float4 v = *(const float4*)src;
    u16* dst = (c8 < 4) ? &qs[i * 40 + c8 * 8] : &ks[i * 40 + (c8 - 4) * 8];
    *(float4*)dst = v;
  }
  __syncthreads();
  const int lane = tid & 63, wv = tid >> 6;
  const int cl = lane & 15, g = lane >> 4;
  const int kc = g * 8;
  // QK^T: e[i = 16wv+4g+r][j = nt*16+cl]
  f32x4 eacc[6];
  {
    f16x8 aq = *(const f16x8*)&qs[(wv * 16 + cl) * 40 + kc];
#pragma unroll
    for (int nt = 0; nt < 6; ++nt) {
      f16x8 bk = *(const f16x8*)&ks[(nt * 16 + cl) * 40 + kc];
      f32x4 zz = {0.f, 0.f, 0.f, 0.f};
      eacc[nt] = __builtin_amdgcn_mfma_f32_16x16x32_f16(aq, bk, zz, 0, 0, 0);
    }
  }
  // wave softmax per row r: max/sum across 6 nt + 16 col-lanes
  float mx[4], sm[4];
#pragma unroll
  for (int r = 0; r < 4; ++r) {
    int i = wv * 16 + 4 * g + r;
    float m = -1e30f;
#pragma unroll
    for (int nt = 0; nt < 6; ++nt) {
      float e = eacc[nt][r];
      if (z && (nt * 16 + cl) == i) { e = -1e30f; eacc[nt][r] = e; }
      m = fmaxf(m, e);
    }
    m = fmaxf(m, __shfl_xor(m, 1));
    m = fmaxf(m, __shfl_xor(m, 2));
    m = fmaxf(m, __shfl_xor(m, 4));
    m = fmaxf(m, __shfl_xor(m, 8));
    float s = 0.f;
#pragma unroll
    for (int nt = 0; nt < 6; ++nt) {
      float pv = __expf(eacc[nt][r] - m);
      eacc[nt][r] = pv;
      s += pv;
    }
    s += __shfl_xor(s, 1);
    s += __shfl_xor(s, 2);
    s += __shfl_xor(s, 4);
    s += __shfl_xor(s, 8);
    mx[r] = m; sm[r] = s;
  }
#pragma unroll
  for (int r = 0; r < 4; ++r) {
    int i = wv * 16 + 4 * g + r;
#pragma unroll
    for (int nt = 0; nt < 6; ++nt)
      probs[i * 104 + nt * 16 + cl] = f2h(eacc[nt][r]);
    if (cl == 0) {
      size_t sidx = z ? ((size_t)(b * 96 + i) * 96 + p) : ((size_t)(b * 96 + p) * 96 + i);
      (z ? mH : mW)[sidx] = mx[r];
      (z ? sH : sW)[sidx] = sm[r];
    }
  }
  __syncthreads();
  // PV: out'[c][i] = sum_j probs[i][j] * V[c][j]
  const u16* Vp = z ? vHp : vWp;
  u16* tOut = z ? tmpH : tmpW;
  const int w0 = wv * 16;
  f16x8 af[3];
#pragma unroll
  for (int kt = 0; kt < 3; ++kt)
    af[kt] = *(const f16x8*)&probs[(w0 + cl) * 104 + kt * 32 + kc];
  const size_t vbase = (size_t)(b * 96 + p) * 24576;
  for (int half = 0; half < 2; ++half) {
    for (int idx = tid; idx < 1536; idx += 384) {
      int r = idx / 12, c4 = idx % 12;
      *(float4*)&vbuf[r * 104 + c4 * 8] = *(const float4*)(Vp + vbase + (size_t)(half * 128 + r) * 96 + c4 * 8);
    }
    __syncthreads();
    f32x4 acc[8];
#pragma unroll
    for (int nt = 0; nt < 8; ++nt) {
      f32x4 a = {0.f, 0.f, 0.f, 0.f};
#pragma unroll
      for (int kt = 0; kt < 3; ++kt) {
        f16x8 bf = *(const f16x8*)&vbuf[(nt * 16 + cl) * 104 + kt * 32 + kc];
        a = __builtin_amdgcn_mfma_f32_16x16x32_f16(af[kt], bf, a, 0, 0, 0);
      }
      acc[nt] = a;
    }
    __syncthreads();
#pragma unroll
    for (int nt = 0; nt < 8; ++nt) {
      int c2 = nt * 16 + cl;
      int wr = w0 + (g << 2);
#pragma unroll
      for (int r = 0; r < 4; ++r) vbuf[c2 * 104 + wr + r] = f2h(acc[nt][r]);
    }
    __syncthreads();
    for (int idx = tid; idx < 1536; idx += 384) {
      int r = idx / 12, c4 = idx % 12;
      *(float4*)(tOut + vbase + (size_t)(half * 128 + r) * 96 + c4 * 8) = *(const float4*)&vbuf[r * 104 + c4 * 8];
    }
    __syncthreads();
  }
}

// Exact concat-softmax rescale: m=max(mh,mw), s=sh*e^(mh-m)+sw*e^(mw-m); scl*=gamma/s.
__global__ __launch_bounds__(256) void scl_k(const float* __restrict__ mH, const float* __restrict__ sH,
                                             const float* __restrict__ mW, const float* __restrict__ sW,
                                             const float* __restrict__ gammaP, float* __restrict__ sclH,
                                             float* __restrict__ sclW) {
  int i = blockIdx.x * 256 + threadIdx.x;
  if (i >= Bn * 9216) return;
  float mh = mH[i], mw = mW[i];
  float m = fmaxf(mh, mw);
  float eh = __expf(mh - m), ew = __expf(mw - m);
  float s = sH[i] * eh + sW[i] * ew;
  float g = gammaP[0] / s;
  sclH[i] = g * eh;
  sclW[i] = g * ew;
}

// out[b][c][h][w] = x + tmpH[b][w][c][h]*sclH[h][w] + tmpW[b][h][c][w]*sclW[h][w]
__global__ __launch_bounds__(256) void tkomb(const u16* __restrict__ tmpH, const u16* __restrict__ tmpW,
                                             const float* __restrict__ x, const float* __restrict__ sclH,
                                             const float* __restrict__ sclW, float* __restrict__ out) {
  __shared__ u16 t[96][108];
  const int c = blockIdx.x, b = blockIdx.y;
  const int tid = threadIdx.x;
  for (int idx = tid; idx < 2304; idx += 256) {
    int w_ = idx / 24, h4 = idx % 24;
    *(ushort4*)&t[w_][h4 * 4] =
        *(const ushort4*)(tmpH + ((size_t)(b * 96 + w_) * 256 + c) * 96 + h4 * 4);
  }
  __syncthreads();
  for (int idx = tid; idx < 2304; idx += 256) {
    int h_ = idx / 24, w4 = idx % 24;
    size_t go = ((size_t)(b * 256 + c) * 96 + h_) * 96 + w4 * 4;
    float4 xv = *(const float4*)(x + go);
    ushort4 wvv = *(const ushort4*)(tmpW + ((size_t)(b * 96 + h_) * 256 + c) * 96 + w4 * 4);
    float4 sh4 = *(const float4*)(sclH + (size_t)(b * 96 + h_) * 96 + w4 * 4);
    float4 sw4 = *(const float4*)(sclW + (size_t)(b * 96 + h_) * 96 + w4 * 4);
    float4 ov;
    ov.x = xv.x + h2f(t[w4 * 4 + 0][h_]) * sh4.x + h2f(wvv.x) * sw4.x;
    ov.y = xv.y + h2f(t[w4 * 4 + 1][h_]) * sh4.y + h2f(wvv.y) * sw4.y;
    ov.z = xv.z + h2f(t[w4 * 4 + 2][h_]) * sh4.z + h2f(wvv.z) * sw4.z;
    ov.w = xv.w + h2f(t[w4 * 4 + 3][h_]) * sh4.w + h2f(wvv.w) * sw4.w;
    *(float4*)(out + go) = ov;
  }
}

extern "C" void kernel_launch(void* const* d_in, const int* in_sizes, int n_in,
                              void* d_out, int out_size, void* d_ws, size_t ws_size,
                              hipStream_t stream) {
  const float* x0 = (const float*)d_in[0];
  const float* x1 = (const float*)d_in[1];
  const float* wq0 = (const float*)d_in[2];
  const float* bq0 = (const float*)d_in[3];
  const float* wk0 = (const float*)d_in[4];
  const float* bk0 = (const float*)d_in[5];
  const float* wv0 = (const float*)d_in[6];
  const float* bv0 = (const float*)d_in[7];
  const float* wq1 = (const float*)d_in[8];
  const float* bq1 = (const float*)d_in[9];
  const float* wk1 = (const float*)d_in[10];
  const float* bk1 = (const float*)d_in[11];
  const float* wv1 = (const float*)d_in[12];
  const float* bv1 = (const float*)d_in[13];
  const float* gamma = (const float*)d_in[14];
  float* out = (float*)d_out;

  char* ws = (char*)d_ws;
  size_t off = 0;
  auto alloc = [&](size_t bytes) -> void* {
    void* ptr = ws + off;
    off += (bytes + 255) & ~(size_t)255;
    return ptr;
  };
  const size_t SZ_P = (size_t)Bn * NHW * 64 * 2;   // 9.4 MB (f16)
  const size_t SZ_V = (size_t)Bn * NHW * Cn * 2;   // 37.7 MB
  const size_t SZ_S = (size_t)Bn * 9216 * 4;       // 294 KB
  u16* Pt0 = (u16*)alloc(SZ_P);
  u16* Pt1 = (u16*)alloc(SZ_P);
  u16* vW0 = (u16*)alloc(SZ_V);
  u16* vW1 = (u16*)alloc(SZ_V);
  u16* vH0 = (u16*)alloc(SZ_V);
  u16* vH1 = (u16*)alloc(SZ_V);
  u16* tmpW = (u16*)alloc(SZ_V);
  u16* tmpH = (u16*)alloc(SZ_V);
  u16* Wall0 = (u16*)alloc(320 * 256 * 2);
  u16* Wall1 = (u16*)alloc(320 * 256 * 2);
  float* ball0 = (float*)alloc(320 * 4);
  float* ball1 = (float*)alloc(320 * 4);
  float* mH = (float*)alloc(SZ_S);
  float* sH = (float*)alloc(SZ_S);
  float* mW = (float*)alloc(SZ_S);
  float* sW = (float*)alloc(SZ_S);
  float* sclH = (float*)alloc(SZ_S);
  float* sclW = (float*)alloc(SZ_S);
  (void)ws_size; (void)in_sizes; (void)n_in; (void)out_size;

  pack_all<<<320, 256, 0, stream>>>(wq0, bq0, wk0, bk0, wv0, bv0, Wall0, ball0);
  pack_all<<<320, 256, 0, stream>>>(wq1, bq1, wk1, bk1, wv1, bv1, Wall1, ball1);

  dim3 gp(96, Bn), gc(256, Bn), gt(256, Bn, 2), ga(96, Bn, 2);
  proj_all<<<gp, 256, 0, stream>>>(x0, Wall0, ball0, Pt0, vW0);
  proj_all<<<gp, 256, 0, stream>>>(x1, Wall1, ball1, Pt1, vW1);
  vtrans<<<gt, 256, 0, stream>>>(vW0, vW1, vH0, vH1);

  // pair 0: cat0 = gamma * attend(q1, k0, v0) + x0
  attn_fused<<<ga, 384, 0, stream>>>(Pt1, Pt0, vW0, vH0, mW, sW, mH, sH, tmpW, tmpH);
  scl_k<<<288, 256, 0, stream>>>(mH, sH, mW, sW, gamma, sclH, sclW);
  tkomb<<<gc, 256, 0, stream>>>(tmpH, tmpW, x0, sclH, sclW, out);

  // pair 1: cat1 = gamma * attend(q0, k1, v1) + x1
  attn_fused<<<ga, 384, 0, stream>>>(Pt0, Pt1, vW1, vH1, mW, sW, mH, sH, tmpW, tmpH);
  scl_k<<<288, 256, 0, stream>>>(mH, sH, mW, sW, gamma, sclH, sclW);
  tkomb<<<gc, 256, 0, stream>>>(tmpH, tmpW, x1, sclH, sclW, out + (size_t)Bn * Cn * NHW);
}